// Round 6
// baseline (504.230 us; speedup 1.0000x reference)
//
#include <hip/hip_runtime.h>
#include <math.h>

#define N_NODES 50000
#define N_EDGES 800000
#define F_IN    86
#define H_DIM   128
#define ED_DIM  16
#define C_CLS   18
#define G_GRAPHS 64
#define NEG_SLOPE 0.2f
#define SCAN_BLOCKS ((N_NODES + 255) / 256)   // 196
#define NPB  6250                              // nodes per XCD bin (50000/8)
#define ECH  4096                              // edges per chunk
#define NCH  ((N_EDGES + ECH - 1) / ECH)       // 196 chunks

typedef _Float16 h2v   __attribute__((ext_vector_type(2)));
typedef _Float16 half8 __attribute__((ext_vector_type(8)));
typedef float    f4v   __attribute__((ext_vector_type(4)));

__device__ __forceinline__ void atomicMaxFloat(float* addr, float val) {
    if (val >= 0.0f) atomicMax((int*)addr, __float_as_int(val));
    else             atomicMin((unsigned int*)addr, __float_as_uint(val));
}

// zero cnt (blocks 0..SCAN_BLOCKS-1); ve1/ve2 + zero pooled (block SCAN_BLOCKS)
__global__ void prep(int* __restrict__ cnt, float* __restrict__ pooled,
                     const float* __restrict__ We1, const float* __restrict__ ae1,
                     const float* __restrict__ We2, const float* __restrict__ ae2,
                     float* __restrict__ ve1, float* __restrict__ ve2) {
    int b = blockIdx.x, t = threadIdx.x;
    if (b < SCAN_BLOCKS) {
        int i = b * 256 + t;
        if (i < N_NODES) cnt[i] = 0;
    } else {
        if (t < ED_DIM) {
            float s = 0.f;
            for (int h = 0; h < H_DIM; ++h) s += We1[t * H_DIM + h] * ae1[h];
            ve1[t] = s;
        } else if (t < 2 * ED_DIM) {
            int j = t - ED_DIM;
            float s = 0.f;
            for (int h = 0; h < H_DIM; ++h) s += We2[j * H_DIM + h] * ae2[h];
            ve2[j] = s;
        }
        for (int i = t; i < G_GRAPHS * H_DIM; i += 256) pooled[i] = 0.f;
    }
}

// XCD-binned histogram: bin = blockIdx&7 (round-robin -> same XCD), so cnt
// atomics for a given dst range stay in one XCD's L2.
__global__ void hist_binned(const int* __restrict__ dst, int* __restrict__ cnt) {
    int bin = blockIdx.x & 7, chunk = blockIdx.x >> 3;
    int lo = bin * NPB, hi = min(lo + NPB, N_NODES);
    int e1 = min(chunk * ECH + ECH, N_EDGES);
    for (int e = chunk * ECH + threadIdx.x; e < e1; e += 256) {
        int d = dst[e];
        if (d >= lo && d < hi) atomicAdd(&cnt[d], 1);
    }
}

// single-block exclusive scan of cnt[0..N_NODES) -> row_ptr, fill
__global__ __launch_bounds__(1024)
void scan_all(const int* __restrict__ cnt, int* __restrict__ row_ptr,
              int* __restrict__ fill) {
    const int SEG = (N_NODES + 1023) / 1024;   // 49
    int t = threadIdx.x;
    int base = t * SEG;
    int s = 0;
    for (int i = 0; i < SEG; ++i) {
        int idx = base + i;
        if (idx < N_NODES) s += cnt[idx];
    }
    int lane = t & 63, wv = t >> 6;
    int incl = s;
    for (int o = 1; o < 64; o <<= 1) {
        int u = __shfl_up(incl, o);
        if (lane >= o) incl += u;
    }
    __shared__ int wsum[16];
    __shared__ int woff[16];
    if (lane == 63) wsum[wv] = incl;
    __syncthreads();
    if (t == 0) {
        int a = 0;
        for (int i = 0; i < 16; ++i) { woff[i] = a; a += wsum[i]; }
    }
    __syncthreads();
    int run = woff[wv] + incl - s;   // exclusive prefix of this thread's segment
    for (int i = 0; i < SEG; ++i) {
        int idx = base + i;
        if (idx < N_NODES) {
            row_ptr[idx] = run;
            fill[idx] = run;
            run += cnt[idx];
        }
    }
    if (t == 1023) row_ptr[N_NODES] = N_EDGES;
}

// XCD-binned scatter: bin = blockIdx&7 handles dst in [bin*NPB,(bin+1)*NPB).
// fill atomics + perm writes for a bin stay in one XCD's L2 (~0.8 MB region),
// so perm lines fill completely before writeback. Packs {src, fp16 d1, fp16 d2}.
__global__ void scatter_binned(const int* __restrict__ src, const int* __restrict__ dst,
                               const float* __restrict__ ea,
                               const float* __restrict__ ve1, const float* __restrict__ ve2,
                               int* __restrict__ fill, int2* __restrict__ perm) {
    int bin = blockIdx.x & 7, chunk = blockIdx.x >> 3;
    int lo = bin * NPB, hi = min(lo + NPB, N_NODES);
    int e1 = min(chunk * ECH + ECH, N_EDGES);
    for (int e = chunk * ECH + threadIdx.x; e < e1; e += 256) {
        int d = dst[e];
        if (d < lo || d >= hi) continue;
        const float4* p = (const float4*)(ea + (size_t)e * ED_DIM);
        float4 v0 = p[0], v1 = p[1], v2 = p[2], v3 = p[3];
        float s1 = v0.x*ve1[0] + v0.y*ve1[1] + v0.z*ve1[2] + v0.w*ve1[3]
                 + v1.x*ve1[4] + v1.y*ve1[5] + v1.z*ve1[6] + v1.w*ve1[7]
                 + v2.x*ve1[8] + v2.y*ve1[9] + v2.z*ve1[10] + v2.w*ve1[11]
                 + v3.x*ve1[12] + v3.y*ve1[13] + v3.z*ve1[14] + v3.w*ve1[15];
        float s2 = v0.x*ve2[0] + v0.y*ve2[1] + v0.z*ve2[2] + v0.w*ve2[3]
                 + v1.x*ve2[4] + v1.y*ve2[5] + v1.z*ve2[6] + v1.w*ve2[7]
                 + v2.x*ve2[8] + v2.y*ve2[9] + v2.z*ve2[10] + v2.w*ve2[11]
                 + v3.x*ve2[12] + v3.y*ve2[13] + v3.z*ve2[14] + v3.w*ve2[15];
        h2v dv;
        dv.x = (_Float16)s1;
        dv.y = (_Float16)s2;
        int pos = atomicAdd(&fill[d], 1);
        perm[pos] = make_int2(src[e], __builtin_bit_cast(int, dv));
    }
}

// conv1 GEMM + fused node dots. h = fp16(x @ W1), K=86 padded to 96.
#define KP1 104
__global__ __launch_bounds__(256)
void gemm1(const float* __restrict__ in, const float* __restrict__ W,
           const float* __restrict__ a_s, const float* __restrict__ a_d,
           _Float16* __restrict__ hout, float* __restrict__ hs, float* __restrict__ hd) {
    __shared__ __attribute__((aligned(16))) _Float16 Asm[64 * KP1];
    __shared__ __attribute__((aligned(16))) _Float16 Bsm[128 * KP1];
    __shared__ float sdots[64][2][2];
    int tid = threadIdx.x;
    int n0 = blockIdx.x * 64;

    const float2* in2 = (const float2*)(in + (size_t)n0 * F_IN);
    for (int idx = tid; idx < 64 * (F_IN / 2); idx += 256) {
        int r = idx / (F_IN / 2), k2 = idx - r * (F_IN / 2);
        float2 v = (n0 + r < N_NODES) ? in2[idx] : make_float2(0.f, 0.f);
        Asm[r * KP1 + 2 * k2]     = (_Float16)v.x;
        Asm[r * KP1 + 2 * k2 + 1] = (_Float16)v.y;
    }
    for (int idx = tid; idx < 64 * (96 - F_IN); idx += 256) {
        int r = idx / (96 - F_IN), k = F_IN + idx - r * (96 - F_IN);
        Asm[r * KP1 + k] = (_Float16)0.f;
    }
    const float4* W4 = (const float4*)W;
    for (int idx = tid; idx < F_IN * 32; idx += 256) {
        float4 v = W4[idx];
        int k = idx >> 5, n = (idx & 31) * 4;
        Bsm[(n + 0) * KP1 + k] = (_Float16)v.x;
        Bsm[(n + 1) * KP1 + k] = (_Float16)v.y;
        Bsm[(n + 2) * KP1 + k] = (_Float16)v.z;
        Bsm[(n + 3) * KP1 + k] = (_Float16)v.w;
    }
    for (int idx = tid; idx < 128 * (96 - F_IN); idx += 256) {
        int n = idx / (96 - F_IN), k = F_IN + idx - n * (96 - F_IN);
        Bsm[n * KP1 + k] = (_Float16)0.f;
    }
    __syncthreads();

    int wave = tid >> 6, lane = tid & 63;
    int wm = (wave & 1) * 32, wn = (wave >> 1) * 64;
    int m16 = lane & 15, quad = lane >> 4;

    f4v acc[2][4];
#pragma unroll
    for (int t = 0; t < 2; ++t)
#pragma unroll
        for (int c = 0; c < 4; ++c) acc[t][c] = (f4v){0.f, 0.f, 0.f, 0.f};

#pragma unroll
    for (int kk = 0; kk < 96 / 32; ++kk) {
        int koff = kk * 32 + quad * 8;
        half8 a0 = *(const half8*)&Asm[(wm + m16) * KP1 + koff];
        half8 a1 = *(const half8*)&Asm[(wm + 16 + m16) * KP1 + koff];
#pragma unroll
        for (int c = 0; c < 4; ++c) {
            half8 b = *(const half8*)&Bsm[(wn + c * 16 + m16) * KP1 + koff];
            acc[0][c] = __builtin_amdgcn_mfma_f32_16x16x32_f16(a0, b, acc[0][c], 0, 0, 0);
            acc[1][c] = __builtin_amdgcn_mfma_f32_16x16x32_f16(a1, b, acc[1][c], 0, 0, 0);
        }
    }

    float asv[4], adv[4];
#pragma unroll
    for (int c = 0; c < 4; ++c) {
        asv[c] = a_s[wn + c * 16 + m16];
        adv[c] = a_d[wn + c * 16 + m16];
    }
#pragma unroll
    for (int t = 0; t < 2; ++t)
#pragma unroll
        for (int r = 0; r < 4; ++r) {
            float ps = 0.f, pd = 0.f;
#pragma unroll
            for (int c = 0; c < 4; ++c) {
                float v = acc[t][c][r];
                ps += v * asv[c];
                pd += v * adv[c];
            }
#pragma unroll
            for (int o = 1; o < 16; o <<= 1) {
                ps += __shfl_xor(ps, o);
                pd += __shfl_xor(pd, o);
            }
            if (m16 == 0) {
                int row = wm + t * 16 + quad * 4 + r;
                sdots[row][wn >> 6][0] = ps;
                sdots[row][wn >> 6][1] = pd;
            }
        }
#pragma unroll
    for (int t = 0; t < 2; ++t)
#pragma unroll
        for (int c = 0; c < 4; ++c)
#pragma unroll
            for (int r = 0; r < 4; ++r) {
                int row = n0 + wm + t * 16 + quad * 4 + r;
                if (row < N_NODES)
                    hout[(size_t)row * H_DIM + wn + c * 16 + m16] = (_Float16)acc[t][c][r];
            }
    __syncthreads();
    if (tid < 64) {
        int row = n0 + tid;
        if (row < N_NODES) {
            hs[row] = sdots[tid][0][0] + sdots[tid][1][0];
            hd[row] = sdots[tid][0][1] + sdots[tid][1][1];
        }
    }
}

// conv2 GEMM + fused node dots. fp16 input, K=128.
#define KP2 136
__global__ __launch_bounds__(256)
void gemm2(const _Float16* __restrict__ in, const float* __restrict__ W,
           const float* __restrict__ a_s, const float* __restrict__ a_d,
           _Float16* __restrict__ hout, float* __restrict__ hs, float* __restrict__ hd) {
    __shared__ __attribute__((aligned(16))) _Float16 Asm[64 * KP2];
    __shared__ __attribute__((aligned(16))) _Float16 Bsm[128 * KP2];
    __shared__ float sdots[64][2][2];
    int tid = threadIdx.x;
    int n0 = blockIdx.x * 64;

    const half8* in8 = (const half8*)(in + (size_t)n0 * H_DIM);
    for (int idx = tid; idx < 64 * 16; idx += 256) {
        int r = idx >> 4, k8 = idx & 15;
        half8 v = (n0 + r < N_NODES) ? in8[idx]
                                     : (half8){0, 0, 0, 0, 0, 0, 0, 0};
        *(half8*)&Asm[r * KP2 + k8 * 8] = v;
    }
    const float4* W4 = (const float4*)W;
    for (int idx = tid; idx < 128 * 32; idx += 256) {
        float4 v = W4[idx];
        int k = idx >> 5, n = (idx & 31) * 4;
        Bsm[(n + 0) * KP2 + k] = (_Float16)v.x;
        Bsm[(n + 1) * KP2 + k] = (_Float16)v.y;
        Bsm[(n + 2) * KP2 + k] = (_Float16)v.z;
        Bsm[(n + 3) * KP2 + k] = (_Float16)v.w;
    }
    __syncthreads();

    int wave = tid >> 6, lane = tid & 63;
    int wm = (wave & 1) * 32, wn = (wave >> 1) * 64;
    int m16 = lane & 15, quad = lane >> 4;

    f4v acc[2][4];
#pragma unroll
    for (int t = 0; t < 2; ++t)
#pragma unroll
        for (int c = 0; c < 4; ++c) acc[t][c] = (f4v){0.f, 0.f, 0.f, 0.f};

#pragma unroll
    for (int kk = 0; kk < 128 / 32; ++kk) {
        int koff = kk * 32 + quad * 8;
        half8 a0 = *(const half8*)&Asm[(wm + m16) * KP2 + koff];
        half8 a1 = *(const half8*)&Asm[(wm + 16 + m16) * KP2 + koff];
#pragma unroll
        for (int c = 0; c < 4; ++c) {
            half8 b = *(const half8*)&Bsm[(wn + c * 16 + m16) * KP2 + koff];
            acc[0][c] = __builtin_amdgcn_mfma_f32_16x16x32_f16(a0, b, acc[0][c], 0, 0, 0);
            acc[1][c] = __builtin_amdgcn_mfma_f32_16x16x32_f16(a1, b, acc[1][c], 0, 0, 0);
        }
    }

    float asv[4], adv[4];
#pragma unroll
    for (int c = 0; c < 4; ++c) {
        asv[c] = a_s[wn + c * 16 + m16];
        adv[c] = a_d[wn + c * 16 + m16];
    }
#pragma unroll
    for (int t = 0; t < 2; ++t)
#pragma unroll
        for (int r = 0; r < 4; ++r) {
            float ps = 0.f, pd = 0.f;
#pragma unroll
            for (int c = 0; c < 4; ++c) {
                float v = acc[t][c][r];
                ps += v * asv[c];
                pd += v * adv[c];
            }
#pragma unroll
            for (int o = 1; o < 16; o <<= 1) {
                ps += __shfl_xor(ps, o);
                pd += __shfl_xor(pd, o);
            }
            if (m16 == 0) {
                int row = wm + t * 16 + quad * 4 + r;
                sdots[row][wn >> 6][0] = ps;
                sdots[row][wn >> 6][1] = pd;
            }
        }
#pragma unroll
    for (int t = 0; t < 2; ++t)
#pragma unroll
        for (int c = 0; c < 4; ++c)
#pragma unroll
            for (int r = 0; r < 4; ++r) {
                int row = n0 + wm + t * 16 + quad * 4 + r;
                if (row < N_NODES)
                    hout[(size_t)row * H_DIM + wn + c * 16 + m16] = (_Float16)acc[t][c][r];
            }
    __syncthreads();
    if (tid < 64) {
        int row = n0 + tid;
        if (row < N_NODES) {
            hs[row] = sdots[tid][0][0] + sdots[tid][1][0];
            hd[row] = sdots[tid][0][1] + sdots[tid][1][1];
        }
    }
}

// One wave per dst node, single-pass softmax (|alpha| small; exp w/o max-sub).
template<int DOT>
__global__ void gat_node(const int* __restrict__ row_ptr, const int2* __restrict__ perm,
                         const float* __restrict__ hs, const float* __restrict__ hd,
                         const _Float16* __restrict__ h, const float* __restrict__ bias,
                         _Float16* __restrict__ out) {
    int n = blockIdx.x * 4 + (threadIdx.x >> 6);
    int lane = threadIdx.x & 63;
    if (n >= N_NODES) return;
    int q = lane >> 4, m = lane & 15;
    int r0 = row_ptr[n], r1 = row_ptr[n + 1];
    float hdn = hd[n];

    float acc[8];
#pragma unroll
    for (int k = 0; k < 8; ++k) acc[k] = 0.f;
    float denl = 0.f;

    for (int c = r0; c < r1; c += 64) {
        int i = c + lane;
        float w = 0.f;
        int s = 0;
        if (i < r1) {
            int2 p = perm[i];
            s = p.x;
            h2v dv = __builtin_bit_cast(h2v, p.y);
            float dotv = (DOT == 1) ? (float)dv.x : (float)dv.y;
            float t = hs[s] + hdn + dotv;
            t = (t > 0.f) ? t : NEG_SLOPE * t;
            w = expf(t);
        }
        denl += w;
        int lim = min(64, r1 - c);
        int njj = (lim + 3) >> 2;
        for (int jj = 0; jj < njj; ++jj) {
            int j = (jj << 2) + q;
            float wj = __shfl(w, j);
            int sj = __shfl(s, j);
            half8 v = *(const half8*)&h[(size_t)sj * H_DIM + m * 8];
#pragma unroll
            for (int k = 0; k < 8; ++k) acc[k] += wj * (float)v[k];
        }
    }
#pragma unroll
    for (int k = 0; k < 8; ++k) {
        acc[k] += __shfl_xor(acc[k], 16);
        acc[k] += __shfl_xor(acc[k], 32);
    }
    float den = denl;
#pragma unroll
    for (int o = 32; o > 0; o >>= 1) den += __shfl_xor(den, o);
    float inv = 1.f / fmaxf(den, 1e-16f);

    if (q == 0) {
        float4 b0 = ((const float4*)bias)[2 * m];
        float4 b1 = ((const float4*)bias)[2 * m + 1];
        half8 ov;
        ov[0] = (_Float16)fmaxf(acc[0] * inv + b0.x, 0.f);
        ov[1] = (_Float16)fmaxf(acc[1] * inv + b0.y, 0.f);
        ov[2] = (_Float16)fmaxf(acc[2] * inv + b0.z, 0.f);
        ov[3] = (_Float16)fmaxf(acc[3] * inv + b0.w, 0.f);
        ov[4] = (_Float16)fmaxf(acc[4] * inv + b1.x, 0.f);
        ov[5] = (_Float16)fmaxf(acc[5] * inv + b1.y, 0.f);
        ov[6] = (_Float16)fmaxf(acc[6] * inv + b1.z, 0.f);
        ov[7] = (_Float16)fmaxf(acc[7] * inv + b1.w, 0.f);
        *(half8*)&out[(size_t)n * H_DIM + m * 8] = ov;
    }
}

// pooled[g,t] = max over nodes of P[n,t]; P>=0, pooled pre-zeroed
__global__ void pool_max(const _Float16* __restrict__ P,
                         const int* __restrict__ batch, float* __restrict__ pooled) {
    int t = threadIdx.x;  // 128
    int n0 = blockIdx.x * 64;
    int n1 = min(n0 + 64, N_NODES);
    if (n0 >= N_NODES) return;
    int cur = batch[n0];
    float acc = 0.f;
    for (int n = n0; n < n1; ++n) {
        int g = batch[n];
        if (g != cur) {
            atomicMaxFloat(&pooled[cur * H_DIM + t], acc);
            acc = 0.f;
            cur = g;
        }
        acc = fmaxf(acc, (float)P[(size_t)n * H_DIM + t]);
    }
    atomicMaxFloat(&pooled[cur * H_DIM + t], acc);
}

__global__ void final_logits(const float* __restrict__ pooled, const float* __restrict__ Wl,
                             const float* __restrict__ bl, float* __restrict__ outp) {
    int g = threadIdx.x;  // 64
    if (g >= G_GRAPHS) return;
    float lg[C_CLS];
#pragma unroll
    for (int c = 0; c < C_CLS; ++c) lg[c] = bl[c];
    for (int k = 0; k < H_DIM; ++k) {
        float v = pooled[g * H_DIM + k];
#pragma unroll
        for (int c = 0; c < C_CLS; ++c) lg[c] += v * Wl[k * C_CLS + c];
    }
    float mx = lg[0];
#pragma unroll
    for (int c = 1; c < C_CLS; ++c) mx = fmaxf(mx, lg[c]);
    float se = 0.f;
#pragma unroll
    for (int c = 0; c < C_CLS; ++c) se += expf(lg[c] - mx);
    float lse = logf(se);
#pragma unroll
    for (int c = 0; c < C_CLS; ++c) outp[g * C_CLS + c] = lg[c] - mx - lse;
}

extern "C" void kernel_launch(void* const* d_in, const int* in_sizes, int n_in,
                              void* d_out, int out_size, void* d_ws, size_t ws_size,
                              hipStream_t stream) {
    const float* x     = (const float*)d_in[0];
    const int*   eidx  = (const int*)d_in[1];
    const float* ea    = (const float*)d_in[2];
    const int*   batch = (const int*)d_in[3];
    const float* W1  = (const float*)d_in[4];
    const float* We1 = (const float*)d_in[5];
    const float* as1 = (const float*)d_in[6];
    const float* ad1 = (const float*)d_in[7];
    const float* ae1 = (const float*)d_in[8];
    const float* b1  = (const float*)d_in[9];
    const float* W2  = (const float*)d_in[10];
    const float* We2 = (const float*)d_in[11];
    const float* as2 = (const float*)d_in[12];
    const float* ad2 = (const float*)d_in[13];
    const float* ae2 = (const float*)d_in[14];
    const float* b2  = (const float*)d_in[15];
    const float* Wl  = (const float*)d_in[16];
    const float* bl  = (const float*)d_in[17];
    float* outp = (float*)d_out;

    const int* src = eidx;
    const int* dst = eidx + N_EDGES;

    char* wsb = (char*)d_ws;
    size_t off = 0;
    auto alloc = [&](size_t bytes) { char* p = wsb + off; off += (bytes + 255) & ~(size_t)255; return p; };
    _Float16* h    = (_Float16*)alloc((size_t)N_NODES * H_DIM * 2);
    _Float16* A2   = (_Float16*)alloc((size_t)N_NODES * H_DIM * 2);
    _Float16* P    = (_Float16*)alloc((size_t)N_NODES * H_DIM * 2);
    int2*  perm    = (int2*)alloc((size_t)N_EDGES * 8);
    float* hs      = (float*)alloc(N_NODES * 4);
    float* hd      = (float*)alloc(N_NODES * 4);
    int*   row_ptr = (int*)alloc((N_NODES + 1) * 4);
    int*   fill    = (int*)alloc(N_NODES * 4);
    int*   cnt     = (int*)alloc(N_NODES * 4);
    float* pooled  = (float*)alloc(G_GRAPHS * H_DIM * 4);
    float* ve1     = (float*)alloc(16 * 4);
    float* ve2     = (float*)alloc(16 * 4);

    const int NB4 = (N_NODES + 3) / 4;
    const int GB = (N_NODES + 63) / 64;

    // prep + CSR build (XCD-binned hist/scatter, single-kernel scan)
    prep<<<SCAN_BLOCKS + 1, 256, 0, stream>>>(cnt, pooled, We1, ae1, We2, ae2, ve1, ve2);
    hist_binned<<<NCH * 8, 256, 0, stream>>>(dst, cnt);
    scan_all<<<1, 1024, 0, stream>>>(cnt, row_ptr, fill);
    scatter_binned<<<NCH * 8, 256, 0, stream>>>(src, dst, ea, ve1, ve2, fill, perm);

    // ---- conv1 ----
    gemm1<<<GB, 256, 0, stream>>>(x, W1, as1, ad1, h, hs, hd);
    gat_node<1><<<NB4, 256, 0, stream>>>(row_ptr, perm, hs, hd, h, b1, A2);

    // ---- conv2 ----
    gemm2<<<GB, 256, 0, stream>>>(A2, W2, as2, ad2, h, hs, hd);
    gat_node<2><<<NB4, 256, 0, stream>>>(row_ptr, perm, hs, hd, h, b2, P);

    // ---- pool + classifier ----
    pool_max<<<GB, 128, 0, stream>>>(P, batch, pooled);
    final_logits<<<1, 64, 0, stream>>>(pooled, Wl, bl, outp);
}

// Round 7
// 386.965 us; speedup vs baseline: 1.3030x; 1.3030x over previous
//
#include <hip/hip_runtime.h>
#include <math.h>

#define N_NODES 50000
#define N_EDGES 800000
#define F_IN    86
#define H_DIM   128
#define ED_DIM  16
#define C_CLS   18
#define G_GRAPHS 64
#define NEG_SLOPE 0.2f
#define SCAN_BLOCKS ((N_NODES + 255) / 256)   // 196
#define NPB  6250                              // nodes per XCD bin (50000/8)
#define ECH  4096                              // edges per chunk
#define NCH  ((N_EDGES + ECH - 1) / ECH)       // 196 chunks

typedef _Float16 h2v   __attribute__((ext_vector_type(2)));
typedef _Float16 half8 __attribute__((ext_vector_type(8)));
typedef float    f4v   __attribute__((ext_vector_type(4)));

__device__ __forceinline__ void atomicMaxFloat(float* addr, float val) {
    if (val >= 0.0f) atomicMax((int*)addr, __float_as_int(val));
    else             atomicMin((unsigned int*)addr, __float_as_uint(val));
}

// zero cnt (blocks 0..SCAN_BLOCKS-1); ve1/ve2 + zero pooled (block SCAN_BLOCKS)
__global__ void prep(int* __restrict__ cnt, float* __restrict__ pooled,
                     const float* __restrict__ We1, const float* __restrict__ ae1,
                     const float* __restrict__ We2, const float* __restrict__ ae2,
                     float* __restrict__ ve1, float* __restrict__ ve2) {
    int b = blockIdx.x, t = threadIdx.x;
    if (b < SCAN_BLOCKS) {
        int i = b * 256 + t;
        if (i < N_NODES) cnt[i] = 0;
    } else {
        if (t < ED_DIM) {
            float s = 0.f;
            for (int h = 0; h < H_DIM; ++h) s += We1[t * H_DIM + h] * ae1[h];
            ve1[t] = s;
        } else if (t < 2 * ED_DIM) {
            int j = t - ED_DIM;
            float s = 0.f;
            for (int h = 0; h < H_DIM; ++h) s += We2[j * H_DIM + h] * ae2[h];
            ve2[j] = s;
        }
        for (int i = t; i < G_GRAPHS * H_DIM; i += 256) pooled[i] = 0.f;
    }
}

// plain histogram (one pass over edges)
__global__ void hist_dst(const int* __restrict__ dst, int* __restrict__ cnt) {
    int e = blockIdx.x * blockDim.x + threadIdx.x;
    if (e < N_EDGES) atomicAdd(&cnt[dst[e]], 1);
}

// ---- 3-kernel hierarchical exclusive scan (proven fast) ----
__global__ void scan1(const int* __restrict__ cnt, int* __restrict__ excl,
                      int* __restrict__ bsum) {
    __shared__ int s[256];
    int tid = threadIdx.x;
    int i = blockIdx.x * 256 + tid;
    int v = (i < N_NODES) ? cnt[i] : 0;
    s[tid] = v;
    __syncthreads();
    for (int o = 1; o < 256; o <<= 1) {
        int t = (tid >= o) ? s[tid - o] : 0;
        __syncthreads();
        s[tid] += t;
        __syncthreads();
    }
    if (i < N_NODES) excl[i] = s[tid] - v;
    if (tid == 255) bsum[blockIdx.x] = s[255];
}

__global__ void scan2(int* __restrict__ bsum) {
    __shared__ int s[256];
    int tid = threadIdx.x;
    int v = (tid < SCAN_BLOCKS) ? bsum[tid] : 0;
    s[tid] = v;
    __syncthreads();
    for (int o = 1; o < 256; o <<= 1) {
        int t = (tid >= o) ? s[tid - o] : 0;
        __syncthreads();
        s[tid] += t;
        __syncthreads();
    }
    if (tid < SCAN_BLOCKS) bsum[tid] = s[tid] - v;
}

__global__ void scan3(const int* __restrict__ excl, const int* __restrict__ bsum,
                      int* __restrict__ row_ptr, int* __restrict__ fill) {
    int i = blockIdx.x * 256 + threadIdx.x;
    if (i < N_NODES) {
        int r = excl[i] + bsum[blockIdx.x];
        row_ptr[i] = r;
        fill[i] = r;
    }
    if (i == 0) row_ptr[N_NODES] = N_EDGES;
}

// XCD-binned scatter: bin = blockIdx&7 handles dst in [bin*NPB,(bin+1)*NPB).
// fill atomics + perm writes for a bin stay in one XCD's L2 region.
__global__ void scatter_binned(const int* __restrict__ src, const int* __restrict__ dst,
                               const float* __restrict__ ea,
                               const float* __restrict__ ve1, const float* __restrict__ ve2,
                               int* __restrict__ fill, int2* __restrict__ perm) {
    int bin = blockIdx.x & 7, chunk = blockIdx.x >> 3;
    int lo = bin * NPB, hi = min(lo + NPB, N_NODES);
    int e1 = min(chunk * ECH + ECH, N_EDGES);
    for (int e = chunk * ECH + threadIdx.x; e < e1; e += 256) {
        int d = dst[e];
        if (d < lo || d >= hi) continue;
        const float4* p = (const float4*)(ea + (size_t)e * ED_DIM);
        float4 v0 = p[0], v1 = p[1], v2 = p[2], v3 = p[3];
        float s1 = v0.x*ve1[0] + v0.y*ve1[1] + v0.z*ve1[2] + v0.w*ve1[3]
                 + v1.x*ve1[4] + v1.y*ve1[5] + v1.z*ve1[6] + v1.w*ve1[7]
                 + v2.x*ve1[8] + v2.y*ve1[9] + v2.z*ve1[10] + v2.w*ve1[11]
                 + v3.x*ve1[12] + v3.y*ve1[13] + v3.z*ve1[14] + v3.w*ve1[15];
        float s2 = v0.x*ve2[0] + v0.y*ve2[1] + v0.z*ve2[2] + v0.w*ve2[3]
                 + v1.x*ve2[4] + v1.y*ve2[5] + v1.z*ve2[6] + v1.w*ve2[7]
                 + v2.x*ve2[8] + v2.y*ve2[9] + v2.z*ve2[10] + v2.w*ve2[11]
                 + v3.x*ve2[12] + v3.y*ve2[13] + v3.z*ve2[14] + v3.w*ve2[15];
        h2v dv;
        dv.x = (_Float16)s1;
        dv.y = (_Float16)s2;
        int pos = atomicAdd(&fill[d], 1);
        perm[pos] = make_int2(src[e], __builtin_bit_cast(int, dv));
    }
}

// conv1 GEMM + fused node dots. h = fp16(x @ W1), K=86 padded to 96.
#define KP1 104
__global__ __launch_bounds__(256)
void gemm1(const float* __restrict__ in, const float* __restrict__ W,
           const float* __restrict__ a_s, const float* __restrict__ a_d,
           _Float16* __restrict__ hout, float* __restrict__ hs, float* __restrict__ hd) {
    __shared__ __attribute__((aligned(16))) _Float16 Asm[64 * KP1];
    __shared__ __attribute__((aligned(16))) _Float16 Bsm[128 * KP1];
    __shared__ float sdots[64][2][2];
    int tid = threadIdx.x;
    int n0 = blockIdx.x * 64;

    const float2* in2 = (const float2*)(in + (size_t)n0 * F_IN);
    for (int idx = tid; idx < 64 * (F_IN / 2); idx += 256) {
        int r = idx / (F_IN / 2), k2 = idx - r * (F_IN / 2);
        float2 v = (n0 + r < N_NODES) ? in2[idx] : make_float2(0.f, 0.f);
        Asm[r * KP1 + 2 * k2]     = (_Float16)v.x;
        Asm[r * KP1 + 2 * k2 + 1] = (_Float16)v.y;
    }
    for (int idx = tid; idx < 64 * (96 - F_IN); idx += 256) {
        int r = idx / (96 - F_IN), k = F_IN + idx - r * (96 - F_IN);
        Asm[r * KP1 + k] = (_Float16)0.f;
    }
    const float4* W4 = (const float4*)W;
    for (int idx = tid; idx < F_IN * 32; idx += 256) {
        float4 v = W4[idx];
        int k = idx >> 5, n = (idx & 31) * 4;
        Bsm[(n + 0) * KP1 + k] = (_Float16)v.x;
        Bsm[(n + 1) * KP1 + k] = (_Float16)v.y;
        Bsm[(n + 2) * KP1 + k] = (_Float16)v.z;
        Bsm[(n + 3) * KP1 + k] = (_Float16)v.w;
    }
    for (int idx = tid; idx < 128 * (96 - F_IN); idx += 256) {
        int n = idx / (96 - F_IN), k = F_IN + idx - n * (96 - F_IN);
        Bsm[n * KP1 + k] = (_Float16)0.f;
    }
    __syncthreads();

    int wave = tid >> 6, lane = tid & 63;
    int wm = (wave & 1) * 32, wn = (wave >> 1) * 64;
    int m16 = lane & 15, quad = lane >> 4;

    f4v acc[2][4];
#pragma unroll
    for (int t = 0; t < 2; ++t)
#pragma unroll
        for (int c = 0; c < 4; ++c) acc[t][c] = (f4v){0.f, 0.f, 0.f, 0.f};

#pragma unroll
    for (int kk = 0; kk < 96 / 32; ++kk) {
        int koff = kk * 32 + quad * 8;
        half8 a0 = *(const half8*)&Asm[(wm + m16) * KP1 + koff];
        half8 a1 = *(const half8*)&Asm[(wm + 16 + m16) * KP1 + koff];
#pragma unroll
        for (int c = 0; c < 4; ++c) {
            half8 b = *(const half8*)&Bsm[(wn + c * 16 + m16) * KP1 + koff];
            acc[0][c] = __builtin_amdgcn_mfma_f32_16x16x32_f16(a0, b, acc[0][c], 0, 0, 0);
            acc[1][c] = __builtin_amdgcn_mfma_f32_16x16x32_f16(a1, b, acc[1][c], 0, 0, 0);
        }
    }

    float asv[4], adv[4];
#pragma unroll
    for (int c = 0; c < 4; ++c) {
        asv[c] = a_s[wn + c * 16 + m16];
        adv[c] = a_d[wn + c * 16 + m16];
    }
#pragma unroll
    for (int t = 0; t < 2; ++t)
#pragma unroll
        for (int r = 0; r < 4; ++r) {
            float ps = 0.f, pd = 0.f;
#pragma unroll
            for (int c = 0; c < 4; ++c) {
                float v = acc[t][c][r];
                ps += v * asv[c];
                pd += v * adv[c];
            }
#pragma unroll
            for (int o = 1; o < 16; o <<= 1) {
                ps += __shfl_xor(ps, o);
                pd += __shfl_xor(pd, o);
            }
            if (m16 == 0) {
                int row = wm + t * 16 + quad * 4 + r;
                sdots[row][wn >> 6][0] = ps;
                sdots[row][wn >> 6][1] = pd;
            }
        }
#pragma unroll
    for (int t = 0; t < 2; ++t)
#pragma unroll
        for (int c = 0; c < 4; ++c)
#pragma unroll
            for (int r = 0; r < 4; ++r) {
                int row = n0 + wm + t * 16 + quad * 4 + r;
                if (row < N_NODES)
                    hout[(size_t)row * H_DIM + wn + c * 16 + m16] = (_Float16)acc[t][c][r];
            }
    __syncthreads();
    if (tid < 64) {
        int row = n0 + tid;
        if (row < N_NODES) {
            hs[row] = sdots[tid][0][0] + sdots[tid][1][0];
            hd[row] = sdots[tid][0][1] + sdots[tid][1][1];
        }
    }
}

// conv2 GEMM + fused node dots. fp16 input, K=128.
#define KP2 136
__global__ __launch_bounds__(256)
void gemm2(const _Float16* __restrict__ in, const float* __restrict__ W,
           const float* __restrict__ a_s, const float* __restrict__ a_d,
           _Float16* __restrict__ hout, float* __restrict__ hs, float* __restrict__ hd) {
    __shared__ __attribute__((aligned(16))) _Float16 Asm[64 * KP2];
    __shared__ __attribute__((aligned(16))) _Float16 Bsm[128 * KP2];
    __shared__ float sdots[64][2][2];
    int tid = threadIdx.x;
    int n0 = blockIdx.x * 64;

    const half8* in8 = (const half8*)(in + (size_t)n0 * H_DIM);
    for (int idx = tid; idx < 64 * 16; idx += 256) {
        int r = idx >> 4, k8 = idx & 15;
        half8 v = (n0 + r < N_NODES) ? in8[idx]
                                     : (half8){0, 0, 0, 0, 0, 0, 0, 0};
        *(half8*)&Asm[r * KP2 + k8 * 8] = v;
    }
    const float4* W4 = (const float4*)W;
    for (int idx = tid; idx < 128 * 32; idx += 256) {
        float4 v = W4[idx];
        int k = idx >> 5, n = (idx & 31) * 4;
        Bsm[(n + 0) * KP2 + k] = (_Float16)v.x;
        Bsm[(n + 1) * KP2 + k] = (_Float16)v.y;
        Bsm[(n + 2) * KP2 + k] = (_Float16)v.z;
        Bsm[(n + 3) * KP2 + k] = (_Float16)v.w;
    }
    __syncthreads();

    int wave = tid >> 6, lane = tid & 63;
    int wm = (wave & 1) * 32, wn = (wave >> 1) * 64;
    int m16 = lane & 15, quad = lane >> 4;

    f4v acc[2][4];
#pragma unroll
    for (int t = 0; t < 2; ++t)
#pragma unroll
        for (int c = 0; c < 4; ++c) acc[t][c] = (f4v){0.f, 0.f, 0.f, 0.f};

#pragma unroll
    for (int kk = 0; kk < 128 / 32; ++kk) {
        int koff = kk * 32 + quad * 8;
        half8 a0 = *(const half8*)&Asm[(wm + m16) * KP2 + koff];
        half8 a1 = *(const half8*)&Asm[(wm + 16 + m16) * KP2 + koff];
#pragma unroll
        for (int c = 0; c < 4; ++c) {
            half8 b = *(const half8*)&Bsm[(wn + c * 16 + m16) * KP2 + koff];
            acc[0][c] = __builtin_amdgcn_mfma_f32_16x16x32_f16(a0, b, acc[0][c], 0, 0, 0);
            acc[1][c] = __builtin_amdgcn_mfma_f32_16x16x32_f16(a1, b, acc[1][c], 0, 0, 0);
        }
    }

    float asv[4], adv[4];
#pragma unroll
    for (int c = 0; c < 4; ++c) {
        asv[c] = a_s[wn + c * 16 + m16];
        adv[c] = a_d[wn + c * 16 + m16];
    }
#pragma unroll
    for (int t = 0; t < 2; ++t)
#pragma unroll
        for (int r = 0; r < 4; ++r) {
            float ps = 0.f, pd = 0.f;
#pragma unroll
            for (int c = 0; c < 4; ++c) {
                float v = acc[t][c][r];
                ps += v * asv[c];
                pd += v * adv[c];
            }
#pragma unroll
            for (int o = 1; o < 16; o <<= 1) {
                ps += __shfl_xor(ps, o);
                pd += __shfl_xor(pd, o);
            }
            if (m16 == 0) {
                int row = wm + t * 16 + quad * 4 + r;
                sdots[row][wn >> 6][0] = ps;
                sdots[row][wn >> 6][1] = pd;
            }
        }
#pragma unroll
    for (int t = 0; t < 2; ++t)
#pragma unroll
        for (int c = 0; c < 4; ++c)
#pragma unroll
            for (int r = 0; r < 4; ++r) {
                int row = n0 + wm + t * 16 + quad * 4 + r;
                if (row < N_NODES)
                    hout[(size_t)row * H_DIM + wn + c * 16 + m16] = (_Float16)acc[t][c][r];
            }
    __syncthreads();
    if (tid < 64) {
        int row = n0 + tid;
        if (row < N_NODES) {
            hs[row] = sdots[tid][0][0] + sdots[tid][1][0];
            hd[row] = sdots[tid][0][1] + sdots[tid][1][1];
        }
    }
}

// One wave per dst node, single-pass softmax (|alpha| small; exp w/o max-sub).
template<int DOT>
__global__ void gat_node(const int* __restrict__ row_ptr, const int2* __restrict__ perm,
                         const float* __restrict__ hs, const float* __restrict__ hd,
                         const _Float16* __restrict__ h, const float* __restrict__ bias,
                         _Float16* __restrict__ out) {
    int n = blockIdx.x * 4 + (threadIdx.x >> 6);
    int lane = threadIdx.x & 63;
    if (n >= N_NODES) return;
    int q = lane >> 4, m = lane & 15;
    int r0 = row_ptr[n], r1 = row_ptr[n + 1];
    float hdn = hd[n];

    float acc[8];
#pragma unroll
    for (int k = 0; k < 8; ++k) acc[k] = 0.f;
    float denl = 0.f;

    for (int c = r0; c < r1; c += 64) {
        int i = c + lane;
        float w = 0.f;
        int s = 0;
        if (i < r1) {
            int2 p = perm[i];
            s = p.x;
            h2v dv = __builtin_bit_cast(h2v, p.y);
            float dotv = (DOT == 1) ? (float)dv.x : (float)dv.y;
            float t = hs[s] + hdn + dotv;
            t = (t > 0.f) ? t : NEG_SLOPE * t;
            w = expf(t);
        }
        denl += w;
        int lim = min(64, r1 - c);
        int njj = (lim + 3) >> 2;
        for (int jj = 0; jj < njj; ++jj) {
            int j = (jj << 2) + q;
            float wj = __shfl(w, j);
            int sj = __shfl(s, j);
            half8 v = *(const half8*)&h[(size_t)sj * H_DIM + m * 8];
#pragma unroll
            for (int k = 0; k < 8; ++k) acc[k] += wj * (float)v[k];
        }
    }
#pragma unroll
    for (int k = 0; k < 8; ++k) {
        acc[k] += __shfl_xor(acc[k], 16);
        acc[k] += __shfl_xor(acc[k], 32);
    }
    float den = denl;
#pragma unroll
    for (int o = 32; o > 0; o >>= 1) den += __shfl_xor(den, o);
    float inv = 1.f / fmaxf(den, 1e-16f);

    if (q == 0) {
        float4 b0 = ((const float4*)bias)[2 * m];
        float4 b1 = ((const float4*)bias)[2 * m + 1];
        half8 ov;
        ov[0] = (_Float16)fmaxf(acc[0] * inv + b0.x, 0.f);
        ov[1] = (_Float16)fmaxf(acc[1] * inv + b0.y, 0.f);
        ov[2] = (_Float16)fmaxf(acc[2] * inv + b0.z, 0.f);
        ov[3] = (_Float16)fmaxf(acc[3] * inv + b0.w, 0.f);
        ov[4] = (_Float16)fmaxf(acc[4] * inv + b1.x, 0.f);
        ov[5] = (_Float16)fmaxf(acc[5] * inv + b1.y, 0.f);
        ov[6] = (_Float16)fmaxf(acc[6] * inv + b1.z, 0.f);
        ov[7] = (_Float16)fmaxf(acc[7] * inv + b1.w, 0.f);
        *(half8*)&out[(size_t)n * H_DIM + m * 8] = ov;
    }
}

// pooled[g,t] = max over nodes of P[n,t]; P>=0, pooled pre-zeroed
__global__ void pool_max(const _Float16* __restrict__ P,
                         const int* __restrict__ batch, float* __restrict__ pooled) {
    int t = threadIdx.x;  // 128
    int n0 = blockIdx.x * 64;
    int n1 = min(n0 + 64, N_NODES);
    if (n0 >= N_NODES) return;
    int cur = batch[n0];
    float acc = 0.f;
    for (int n = n0; n < n1; ++n) {
        int g = batch[n];
        if (g != cur) {
            atomicMaxFloat(&pooled[cur * H_DIM + t], acc);
            acc = 0.f;
            cur = g;
        }
        acc = fmaxf(acc, (float)P[(size_t)n * H_DIM + t]);
    }
    atomicMaxFloat(&pooled[cur * H_DIM + t], acc);
}

__global__ void final_logits(const float* __restrict__ pooled, const float* __restrict__ Wl,
                             const float* __restrict__ bl, float* __restrict__ outp) {
    int g = threadIdx.x;  // 64
    if (g >= G_GRAPHS) return;
    float lg[C_CLS];
#pragma unroll
    for (int c = 0; c < C_CLS; ++c) lg[c] = bl[c];
    for (int k = 0; k < H_DIM; ++k) {
        float v = pooled[g * H_DIM + k];
#pragma unroll
        for (int c = 0; c < C_CLS; ++c) lg[c] += v * Wl[k * C_CLS + c];
    }
    float mx = lg[0];
#pragma unroll
    for (int c = 1; c < C_CLS; ++c) mx = fmaxf(mx, lg[c]);
    float se = 0.f;
#pragma unroll
    for (int c = 0; c < C_CLS; ++c) se += expf(lg[c] - mx);
    float lse = logf(se);
#pragma unroll
    for (int c = 0; c < C_CLS; ++c) outp[g * C_CLS + c] = lg[c] - mx - lse;
}

extern "C" void kernel_launch(void* const* d_in, const int* in_sizes, int n_in,
                              void* d_out, int out_size, void* d_ws, size_t ws_size,
                              hipStream_t stream) {
    const float* x     = (const float*)d_in[0];
    const int*   eidx  = (const int*)d_in[1];
    const float* ea    = (const float*)d_in[2];
    const int*   batch = (const int*)d_in[3];
    const float* W1  = (const float*)d_in[4];
    const float* We1 = (const float*)d_in[5];
    const float* as1 = (const float*)d_in[6];
    const float* ad1 = (const float*)d_in[7];
    const float* ae1 = (const float*)d_in[8];
    const float* b1  = (const float*)d_in[9];
    const float* W2  = (const float*)d_in[10];
    const float* We2 = (const float*)d_in[11];
    const float* as2 = (const float*)d_in[12];
    const float* ad2 = (const float*)d_in[13];
    const float* ae2 = (const float*)d_in[14];
    const float* b2  = (const float*)d_in[15];
    const float* Wl  = (const float*)d_in[16];
    const float* bl  = (const float*)d_in[17];
    float* outp = (float*)d_out;

    const int* src = eidx;
    const int* dst = eidx + N_EDGES;

    char* wsb = (char*)d_ws;
    size_t off = 0;
    auto alloc = [&](size_t bytes) { char* p = wsb + off; off += (bytes + 255) & ~(size_t)255; return p; };
    _Float16* h    = (_Float16*)alloc((size_t)N_NODES * H_DIM * 2);
    _Float16* A2   = (_Float16*)alloc((size_t)N_NODES * H_DIM * 2);
    _Float16* P    = (_Float16*)alloc((size_t)N_NODES * H_DIM * 2);
    int2*  perm    = (int2*)alloc((size_t)N_EDGES * 8);
    float* hs      = (float*)alloc(N_NODES * 4);
    float* hd      = (float*)alloc(N_NODES * 4);
    int*   row_ptr = (int*)alloc((N_NODES + 1) * 4);
    int*   fill    = (int*)alloc(N_NODES * 4);
    int*   cnt     = (int*)alloc(N_NODES * 4);
    int*   excl    = (int*)alloc(N_NODES * 4);
    int*   bsum    = (int*)alloc(SCAN_BLOCKS * 4);
    float* pooled  = (float*)alloc(G_GRAPHS * H_DIM * 4);
    float* ve1     = (float*)alloc(16 * 4);
    float* ve2     = (float*)alloc(16 * 4);

    const int EB = (N_EDGES + 255) / 256;
    const int NB4 = (N_NODES + 3) / 4;
    const int GB = (N_NODES + 63) / 64;

    // prep + CSR build (plain hist, 3-kernel scan, XCD-binned scatter)
    prep<<<SCAN_BLOCKS + 1, 256, 0, stream>>>(cnt, pooled, We1, ae1, We2, ae2, ve1, ve2);
    hist_dst<<<EB, 256, 0, stream>>>(dst, cnt);
    scan1<<<SCAN_BLOCKS, 256, 0, stream>>>(cnt, excl, bsum);
    scan2<<<1, 256, 0, stream>>>(bsum);
    scan3<<<SCAN_BLOCKS, 256, 0, stream>>>(excl, bsum, row_ptr, fill);
    scatter_binned<<<NCH * 8, 256, 0, stream>>>(src, dst, ea, ve1, ve2, fill, perm);

    // ---- conv1 ----
    gemm1<<<GB, 256, 0, stream>>>(x, W1, as1, ad1, h, hs, hd);
    gat_node<1><<<NB4, 256, 0, stream>>>(row_ptr, perm, hs, hd, h, b1, A2);

    // ---- conv2 ----
    gemm2<<<GB, 256, 0, stream>>>(A2, W2, as2, ad2, h, hs, hd);
    gat_node<2><<<NB4, 256, 0, stream>>>(row_ptr, perm, hs, hd, h, b2, P);

    // ---- pool + classifier ----
    pool_max<<<GB, 128, 0, stream>>>(P, batch, pooled);
    final_logits<<<1, 64, 0, stream>>>(pooled, Wl, bl, outp);
}

// Round 8
// 357.944 us; speedup vs baseline: 1.4087x; 1.0811x over previous
//
#include <hip/hip_runtime.h>
#include <math.h>

#define N_NODES 50000
#define N_EDGES 800000
#define F_IN    86
#define H_DIM   128
#define ED_DIM  16
#define C_CLS   18
#define G_GRAPHS 64
#define NEG_SLOPE 0.2f
#define SCAN_BLOCKS ((N_NODES + 255) / 256)   // 196

typedef _Float16 h2v   __attribute__((ext_vector_type(2)));
typedef _Float16 half8 __attribute__((ext_vector_type(8)));
typedef float    f4v   __attribute__((ext_vector_type(4)));

__device__ __forceinline__ void atomicMaxFloat(float* addr, float val) {
    if (val >= 0.0f) atomicMax((int*)addr, __float_as_int(val));
    else             atomicMin((unsigned int*)addr, __float_as_uint(val));
}

// zero cnt (blocks 0..SCAN_BLOCKS-1); ve1/ve2 + zero pooled (block SCAN_BLOCKS)
__global__ void prep(int* __restrict__ cnt, float* __restrict__ pooled,
                     const float* __restrict__ We1, const float* __restrict__ ae1,
                     const float* __restrict__ We2, const float* __restrict__ ae2,
                     float* __restrict__ ve1, float* __restrict__ ve2) {
    int b = blockIdx.x, t = threadIdx.x;
    if (b < SCAN_BLOCKS) {
        int i = b * 256 + t;
        if (i < N_NODES) cnt[i] = 0;
    } else {
        if (t < ED_DIM) {
            float s = 0.f;
            for (int h = 0; h < H_DIM; ++h) s += We1[t * H_DIM + h] * ae1[h];
            ve1[t] = s;
        } else if (t < 2 * ED_DIM) {
            int j = t - ED_DIM;
            float s = 0.f;
            for (int h = 0; h < H_DIM; ++h) s += We2[j * H_DIM + h] * ae2[h];
            ve2[j] = s;
        }
        for (int i = t; i < G_GRAPHS * H_DIM; i += 256) pooled[i] = 0.f;
    }
}

// histogram + per-edge rank (the atomicAdd return is the edge's slot in its row)
__global__ void hist_rank(const int* __restrict__ dst, int* __restrict__ cnt,
                          unsigned short* __restrict__ rank) {
    int e = blockIdx.x * blockDim.x + threadIdx.x;
    if (e < N_EDGES) {
        int r = atomicAdd(&cnt[dst[e]], 1);
        rank[e] = (unsigned short)r;
    }
}

// per-block inclusive scan -> excl (within-block exclusive) + block sums
__global__ void scan1(const int* __restrict__ cnt, int* __restrict__ excl,
                      int* __restrict__ bsum) {
    __shared__ int s[256];
    int tid = threadIdx.x;
    int i = blockIdx.x * 256 + tid;
    int v = (i < N_NODES) ? cnt[i] : 0;
    s[tid] = v;
    __syncthreads();
    for (int o = 1; o < 256; o <<= 1) {
        int t = (tid >= o) ? s[tid - o] : 0;
        __syncthreads();
        s[tid] += t;
        __syncthreads();
    }
    if (i < N_NODES) excl[i] = s[tid] - v;
    if (tid == 255) bsum[blockIdx.x] = s[255];
}

// merged scan2+scan3: every block scans the 196 block sums in LDS (cheap,
// redundant) and writes its slice of row_ptr.
__global__ void scan23(const int* __restrict__ excl, const int* __restrict__ bsum,
                       int* __restrict__ row_ptr) {
    __shared__ int s[256];
    int tid = threadIdx.x;
    int v = (tid < SCAN_BLOCKS) ? bsum[tid] : 0;
    s[tid] = v;
    __syncthreads();
    for (int o = 1; o < 256; o <<= 1) {
        int t = (tid >= o) ? s[tid - o] : 0;
        __syncthreads();
        s[tid] += t;
        __syncthreads();
    }
    int boff = s[blockIdx.x] - bsum[blockIdx.x];   // exclusive prefix of this block
    int i = blockIdx.x * 256 + tid;
    if (i < N_NODES) row_ptr[i] = excl[i] + boff;
    if (i == 0) row_ptr[N_NODES] = N_EDGES;
}

// atomic-free scatter: pos = row_ptr[dst] + rank. All loads sequential or
// L2-cached; stores fire-and-forget; 4 independent edges per thread.
__global__ void scatter_plain(const int* __restrict__ src, const int* __restrict__ dst,
                              const float* __restrict__ ea,
                              const float* __restrict__ ve1, const float* __restrict__ ve2,
                              const int* __restrict__ row_ptr,
                              const unsigned short* __restrict__ rank,
                              int2* __restrict__ perm) {
    int base = blockIdx.x * 1024 + threadIdx.x;
#pragma unroll
    for (int u = 0; u < 4; ++u) {
        int e = base + u * 256;
        if (e >= N_EDGES) continue;
        int d = dst[e];
        int pos = row_ptr[d] + rank[e];
        const float4* p = (const float4*)(ea + (size_t)e * ED_DIM);
        float4 v0 = p[0], v1 = p[1], v2 = p[2], v3 = p[3];
        float s1 = v0.x*ve1[0] + v0.y*ve1[1] + v0.z*ve1[2] + v0.w*ve1[3]
                 + v1.x*ve1[4] + v1.y*ve1[5] + v1.z*ve1[6] + v1.w*ve1[7]
                 + v2.x*ve1[8] + v2.y*ve1[9] + v2.z*ve1[10] + v2.w*ve1[11]
                 + v3.x*ve1[12] + v3.y*ve1[13] + v3.z*ve1[14] + v3.w*ve1[15];
        float s2 = v0.x*ve2[0] + v0.y*ve2[1] + v0.z*ve2[2] + v0.w*ve2[3]
                 + v1.x*ve2[4] + v1.y*ve2[5] + v1.z*ve2[6] + v1.w*ve2[7]
                 + v2.x*ve2[8] + v2.y*ve2[9] + v2.z*ve2[10] + v2.w*ve2[11]
                 + v3.x*ve2[12] + v3.y*ve2[13] + v3.z*ve2[14] + v3.w*ve2[15];
        h2v dv;
        dv.x = (_Float16)s1;
        dv.y = (_Float16)s2;
        perm[pos] = make_int2(src[e], __builtin_bit_cast(int, dv));
    }
}

// conv1 GEMM + fused node dots. h = fp16(x @ W1), K=86 padded to 96.
#define KP1 104
__global__ __launch_bounds__(256)
void gemm1(const float* __restrict__ in, const float* __restrict__ W,
           const float* __restrict__ a_s, const float* __restrict__ a_d,
           _Float16* __restrict__ hout, float* __restrict__ hs, float* __restrict__ hd) {
    __shared__ __attribute__((aligned(16))) _Float16 Asm[64 * KP1];
    __shared__ __attribute__((aligned(16))) _Float16 Bsm[128 * KP1];
    __shared__ float sdots[64][2][2];
    int tid = threadIdx.x;
    int n0 = blockIdx.x * 64;

    const float2* in2 = (const float2*)(in + (size_t)n0 * F_IN);
    for (int idx = tid; idx < 64 * (F_IN / 2); idx += 256) {
        int r = idx / (F_IN / 2), k2 = idx - r * (F_IN / 2);
        float2 v = (n0 + r < N_NODES) ? in2[idx] : make_float2(0.f, 0.f);
        Asm[r * KP1 + 2 * k2]     = (_Float16)v.x;
        Asm[r * KP1 + 2 * k2 + 1] = (_Float16)v.y;
    }
    for (int idx = tid; idx < 64 * (96 - F_IN); idx += 256) {
        int r = idx / (96 - F_IN), k = F_IN + idx - r * (96 - F_IN);
        Asm[r * KP1 + k] = (_Float16)0.f;
    }
    const float4* W4 = (const float4*)W;
    for (int idx = tid; idx < F_IN * 32; idx += 256) {
        float4 v = W4[idx];
        int k = idx >> 5, n = (idx & 31) * 4;
        Bsm[(n + 0) * KP1 + k] = (_Float16)v.x;
        Bsm[(n + 1) * KP1 + k] = (_Float16)v.y;
        Bsm[(n + 2) * KP1 + k] = (_Float16)v.z;
        Bsm[(n + 3) * KP1 + k] = (_Float16)v.w;
    }
    for (int idx = tid; idx < 128 * (96 - F_IN); idx += 256) {
        int n = idx / (96 - F_IN), k = F_IN + idx - n * (96 - F_IN);
        Bsm[n * KP1 + k] = (_Float16)0.f;
    }
    __syncthreads();

    int wave = tid >> 6, lane = tid & 63;
    int wm = (wave & 1) * 32, wn = (wave >> 1) * 64;
    int m16 = lane & 15, quad = lane >> 4;

    f4v acc[2][4];
#pragma unroll
    for (int t = 0; t < 2; ++t)
#pragma unroll
        for (int c = 0; c < 4; ++c) acc[t][c] = (f4v){0.f, 0.f, 0.f, 0.f};

#pragma unroll
    for (int kk = 0; kk < 96 / 32; ++kk) {
        int koff = kk * 32 + quad * 8;
        half8 a0 = *(const half8*)&Asm[(wm + m16) * KP1 + koff];
        half8 a1 = *(const half8*)&Asm[(wm + 16 + m16) * KP1 + koff];
#pragma unroll
        for (int c = 0; c < 4; ++c) {
            half8 b = *(const half8*)&Bsm[(wn + c * 16 + m16) * KP1 + koff];
            acc[0][c] = __builtin_amdgcn_mfma_f32_16x16x32_f16(a0, b, acc[0][c], 0, 0, 0);
            acc[1][c] = __builtin_amdgcn_mfma_f32_16x16x32_f16(a1, b, acc[1][c], 0, 0, 0);
        }
    }

    float asv[4], adv[4];
#pragma unroll
    for (int c = 0; c < 4; ++c) {
        asv[c] = a_s[wn + c * 16 + m16];
        adv[c] = a_d[wn + c * 16 + m16];
    }
#pragma unroll
    for (int t = 0; t < 2; ++t)
#pragma unroll
        for (int r = 0; r < 4; ++r) {
            float ps = 0.f, pd = 0.f;
#pragma unroll
            for (int c = 0; c < 4; ++c) {
                float v = acc[t][c][r];
                ps += v * asv[c];
                pd += v * adv[c];
            }
#pragma unroll
            for (int o = 1; o < 16; o <<= 1) {
                ps += __shfl_xor(ps, o);
                pd += __shfl_xor(pd, o);
            }
            if (m16 == 0) {
                int row = wm + t * 16 + quad * 4 + r;
                sdots[row][wn >> 6][0] = ps;
                sdots[row][wn >> 6][1] = pd;
            }
        }
#pragma unroll
    for (int t = 0; t < 2; ++t)
#pragma unroll
        for (int c = 0; c < 4; ++c)
#pragma unroll
            for (int r = 0; r < 4; ++r) {
                int row = n0 + wm + t * 16 + quad * 4 + r;
                if (row < N_NODES)
                    hout[(size_t)row * H_DIM + wn + c * 16 + m16] = (_Float16)acc[t][c][r];
            }
    __syncthreads();
    if (tid < 64) {
        int row = n0 + tid;
        if (row < N_NODES) {
            hs[row] = sdots[tid][0][0] + sdots[tid][1][0];
            hd[row] = sdots[tid][0][1] + sdots[tid][1][1];
        }
    }
}

// conv2 GEMM + fused node dots. fp16 input, K=128.
#define KP2 136
__global__ __launch_bounds__(256)
void gemm2(const _Float16* __restrict__ in, const float* __restrict__ W,
           const float* __restrict__ a_s, const float* __restrict__ a_d,
           _Float16* __restrict__ hout, float* __restrict__ hs, float* __restrict__ hd) {
    __shared__ __attribute__((aligned(16))) _Float16 Asm[64 * KP2];
    __shared__ __attribute__((aligned(16))) _Float16 Bsm[128 * KP2];
    __shared__ float sdots[64][2][2];
    int tid = threadIdx.x;
    int n0 = blockIdx.x * 64;

    const half8* in8 = (const half8*)(in + (size_t)n0 * H_DIM);
    for (int idx = tid; idx < 64 * 16; idx += 256) {
        int r = idx >> 4, k8 = idx & 15;
        half8 v = (n0 + r < N_NODES) ? in8[idx]
                                     : (half8){0, 0, 0, 0, 0, 0, 0, 0};
        *(half8*)&Asm[r * KP2 + k8 * 8] = v;
    }
    const float4* W4 = (const float4*)W;
    for (int idx = tid; idx < 128 * 32; idx += 256) {
        float4 v = W4[idx];
        int k = idx >> 5, n = (idx & 31) * 4;
        Bsm[(n + 0) * KP2 + k] = (_Float16)v.x;
        Bsm[(n + 1) * KP2 + k] = (_Float16)v.y;
        Bsm[(n + 2) * KP2 + k] = (_Float16)v.z;
        Bsm[(n + 3) * KP2 + k] = (_Float16)v.w;
    }
    __syncthreads();

    int wave = tid >> 6, lane = tid & 63;
    int wm = (wave & 1) * 32, wn = (wave >> 1) * 64;
    int m16 = lane & 15, quad = lane >> 4;

    f4v acc[2][4];
#pragma unroll
    for (int t = 0; t < 2; ++t)
#pragma unroll
        for (int c = 0; c < 4; ++c) acc[t][c] = (f4v){0.f, 0.f, 0.f, 0.f};

#pragma unroll
    for (int kk = 0; kk < 128 / 32; ++kk) {
        int koff = kk * 32 + quad * 8;
        half8 a0 = *(const half8*)&Asm[(wm + m16) * KP2 + koff];
        half8 a1 = *(const half8*)&Asm[(wm + 16 + m16) * KP2 + koff];
#pragma unroll
        for (int c = 0; c < 4; ++c) {
            half8 b = *(const half8*)&Bsm[(wn + c * 16 + m16) * KP2 + koff];
            acc[0][c] = __builtin_amdgcn_mfma_f32_16x16x32_f16(a0, b, acc[0][c], 0, 0, 0);
            acc[1][c] = __builtin_amdgcn_mfma_f32_16x16x32_f16(a1, b, acc[1][c], 0, 0, 0);
        }
    }

    float asv[4], adv[4];
#pragma unroll
    for (int c = 0; c < 4; ++c) {
        asv[c] = a_s[wn + c * 16 + m16];
        adv[c] = a_d[wn + c * 16 + m16];
    }
#pragma unroll
    for (int t = 0; t < 2; ++t)
#pragma unroll
        for (int r = 0; r < 4; ++r) {
            float ps = 0.f, pd = 0.f;
#pragma unroll
            for (int c = 0; c < 4; ++c) {
                float v = acc[t][c][r];
                ps += v * asv[c];
                pd += v * adv[c];
            }
#pragma unroll
            for (int o = 1; o < 16; o <<= 1) {
                ps += __shfl_xor(ps, o);
                pd += __shfl_xor(pd, o);
            }
            if (m16 == 0) {
                int row = wm + t * 16 + quad * 4 + r;
                sdots[row][wn >> 6][0] = ps;
                sdots[row][wn >> 6][1] = pd;
            }
        }
#pragma unroll
    for (int t = 0; t < 2; ++t)
#pragma unroll
        for (int c = 0; c < 4; ++c)
#pragma unroll
            for (int r = 0; r < 4; ++r) {
                int row = n0 + wm + t * 16 + quad * 4 + r;
                if (row < N_NODES)
                    hout[(size_t)row * H_DIM + wn + c * 16 + m16] = (_Float16)acc[t][c][r];
            }
    __syncthreads();
    if (tid < 64) {
        int row = n0 + tid;
        if (row < N_NODES) {
            hs[row] = sdots[tid][0][0] + sdots[tid][1][0];
            hd[row] = sdots[tid][0][1] + sdots[tid][1][1];
        }
    }
}

// One wave per dst node, single-pass softmax (|alpha| small; exp w/o max-sub).
template<int DOT>
__global__ void gat_node(const int* __restrict__ row_ptr, const int2* __restrict__ perm,
                         const float* __restrict__ hs, const float* __restrict__ hd,
                         const _Float16* __restrict__ h, const float* __restrict__ bias,
                         _Float16* __restrict__ out) {
    int n = blockIdx.x * 4 + (threadIdx.x >> 6);
    int lane = threadIdx.x & 63;
    if (n >= N_NODES) return;
    int q = lane >> 4, m = lane & 15;
    int r0 = row_ptr[n], r1 = row_ptr[n + 1];
    float hdn = hd[n];

    float acc[8];
#pragma unroll
    for (int k = 0; k < 8; ++k) acc[k] = 0.f;
    float denl = 0.f;

    for (int c = r0; c < r1; c += 64) {
        int i = c + lane;
        float w = 0.f;
        int s = 0;
        if (i < r1) {
            int2 p = perm[i];
            s = p.x;
            h2v dv = __builtin_bit_cast(h2v, p.y);
            float dotv = (DOT == 1) ? (float)dv.x : (float)dv.y;
            float t = hs[s] + hdn + dotv;
            t = (t > 0.f) ? t : NEG_SLOPE * t;
            w = expf(t);
        }
        denl += w;
        int lim = min(64, r1 - c);
        int njj = (lim + 3) >> 2;
        for (int jj = 0; jj < njj; ++jj) {
            int j = (jj << 2) + q;
            float wj = __shfl(w, j);
            int sj = __shfl(s, j);
            half8 v = *(const half8*)&h[(size_t)sj * H_DIM + m * 8];
#pragma unroll
            for (int k = 0; k < 8; ++k) acc[k] += wj * (float)v[k];
        }
    }
#pragma unroll
    for (int k = 0; k < 8; ++k) {
        acc[k] += __shfl_xor(acc[k], 16);
        acc[k] += __shfl_xor(acc[k], 32);
    }
    float den = denl;
#pragma unroll
    for (int o = 32; o > 0; o >>= 1) den += __shfl_xor(den, o);
    float inv = 1.f / fmaxf(den, 1e-16f);

    if (q == 0) {
        float4 b0 = ((const float4*)bias)[2 * m];
        float4 b1 = ((const float4*)bias)[2 * m + 1];
        half8 ov;
        ov[0] = (_Float16)fmaxf(acc[0] * inv + b0.x, 0.f);
        ov[1] = (_Float16)fmaxf(acc[1] * inv + b0.y, 0.f);
        ov[2] = (_Float16)fmaxf(acc[2] * inv + b0.z, 0.f);
        ov[3] = (_Float16)fmaxf(acc[3] * inv + b0.w, 0.f);
        ov[4] = (_Float16)fmaxf(acc[4] * inv + b1.x, 0.f);
        ov[5] = (_Float16)fmaxf(acc[5] * inv + b1.y, 0.f);
        ov[6] = (_Float16)fmaxf(acc[6] * inv + b1.z, 0.f);
        ov[7] = (_Float16)fmaxf(acc[7] * inv + b1.w, 0.f);
        *(half8*)&out[(size_t)n * H_DIM + m * 8] = ov;
    }
}

// pooled[g,t] = max over nodes of P[n,t]; P>=0, pooled pre-zeroed
__global__ void pool_max(const _Float16* __restrict__ P,
                         const int* __restrict__ batch, float* __restrict__ pooled) {
    int t = threadIdx.x;  // 128
    int n0 = blockIdx.x * 64;
    int n1 = min(n0 + 64, N_NODES);
    if (n0 >= N_NODES) return;
    int cur = batch[n0];
    float acc = 0.f;
    for (int n = n0; n < n1; ++n) {
        int g = batch[n];
        if (g != cur) {
            atomicMaxFloat(&pooled[cur * H_DIM + t], acc);
            acc = 0.f;
            cur = g;
        }
        acc = fmaxf(acc, (float)P[(size_t)n * H_DIM + t]);
    }
    atomicMaxFloat(&pooled[cur * H_DIM + t], acc);
}

__global__ void final_logits(const float* __restrict__ pooled, const float* __restrict__ Wl,
                             const float* __restrict__ bl, float* __restrict__ outp) {
    int g = threadIdx.x;  // 64
    if (g >= G_GRAPHS) return;
    float lg[C_CLS];
#pragma unroll
    for (int c = 0; c < C_CLS; ++c) lg[c] = bl[c];
    for (int k = 0; k < H_DIM; ++k) {
        float v = pooled[g * H_DIM + k];
#pragma unroll
        for (int c = 0; c < C_CLS; ++c) lg[c] += v * Wl[k * C_CLS + c];
    }
    float mx = lg[0];
#pragma unroll
    for (int c = 1; c < C_CLS; ++c) mx = fmaxf(mx, lg[c]);
    float se = 0.f;
#pragma unroll
    for (int c = 0; c < C_CLS; ++c) se += expf(lg[c] - mx);
    float lse = logf(se);
#pragma unroll
    for (int c = 0; c < C_CLS; ++c) outp[g * C_CLS + c] = lg[c] - mx - lse;
}

extern "C" void kernel_launch(void* const* d_in, const int* in_sizes, int n_in,
                              void* d_out, int out_size, void* d_ws, size_t ws_size,
                              hipStream_t stream) {
    const float* x     = (const float*)d_in[0];
    const int*   eidx  = (const int*)d_in[1];
    const float* ea    = (const float*)d_in[2];
    const int*   batch = (const int*)d_in[3];
    const float* W1  = (const float*)d_in[4];
    const float* We1 = (const float*)d_in[5];
    const float* as1 = (const float*)d_in[6];
    const float* ad1 = (const float*)d_in[7];
    const float* ae1 = (const float*)d_in[8];
    const float* b1  = (const float*)d_in[9];
    const float* W2  = (const float*)d_in[10];
    const float* We2 = (const float*)d_in[11];
    const float* as2 = (const float*)d_in[12];
    const float* ad2 = (const float*)d_in[13];
    const float* ae2 = (const float*)d_in[14];
    const float* b2  = (const float*)d_in[15];
    const float* Wl  = (const float*)d_in[16];
    const float* bl  = (const float*)d_in[17];
    float* outp = (float*)d_out;

    const int* src = eidx;
    const int* dst = eidx + N_EDGES;

    char* wsb = (char*)d_ws;
    size_t off = 0;
    auto alloc = [&](size_t bytes) { char* p = wsb + off; off += (bytes + 255) & ~(size_t)255; return p; };
    _Float16* h    = (_Float16*)alloc((size_t)N_NODES * H_DIM * 2);
    _Float16* A2   = (_Float16*)alloc((size_t)N_NODES * H_DIM * 2);
    _Float16* P    = (_Float16*)alloc((size_t)N_NODES * H_DIM * 2);
    int2*  perm    = (int2*)alloc((size_t)N_EDGES * 8);
    unsigned short* rank = (unsigned short*)alloc((size_t)N_EDGES * 2);
    float* hs      = (float*)alloc(N_NODES * 4);
    float* hd      = (float*)alloc(N_NODES * 4);
    int*   row_ptr = (int*)alloc((N_NODES + 1) * 4);
    int*   cnt     = (int*)alloc(N_NODES * 4);
    int*   excl    = (int*)alloc(N_NODES * 4);
    int*   bsum    = (int*)alloc(SCAN_BLOCKS * 4);
    float* pooled  = (float*)alloc(G_GRAPHS * H_DIM * 4);
    float* ve1     = (float*)alloc(16 * 4);
    float* ve2     = (float*)alloc(16 * 4);

    const int EB = (N_EDGES + 255) / 256;
    const int NB4 = (N_NODES + 3) / 4;
    const int GB = (N_NODES + 63) / 64;

    // prep + CSR build (rank-trick: scatter has no atomics)
    prep<<<SCAN_BLOCKS + 1, 256, 0, stream>>>(cnt, pooled, We1, ae1, We2, ae2, ve1, ve2);
    hist_rank<<<EB, 256, 0, stream>>>(dst, cnt, rank);
    scan1<<<SCAN_BLOCKS, 256, 0, stream>>>(cnt, excl, bsum);
    scan23<<<SCAN_BLOCKS, 256, 0, stream>>>(excl, bsum, row_ptr);
    scatter_plain<<<(N_EDGES + 1023) / 1024, 256, 0, stream>>>(src, dst, ea, ve1, ve2,
                                                               row_ptr, rank, perm);

    // ---- conv1 ----
    gemm1<<<GB, 256, 0, stream>>>(x, W1, as1, ad1, h, hs, hd);
    gat_node<1><<<NB4, 256, 0, stream>>>(row_ptr, perm, hs, hd, h, b1, A2);

    // ---- conv2 ----
    gemm2<<<GB, 256, 0, stream>>>(A2, W2, as2, ad2, h, hs, hd);
    gat_node<2><<<NB4, 256, 0, stream>>>(row_ptr, perm, hs, hd, h, b2, P);

    // ---- pool + classifier ----
    pool_max<<<GB, 128, 0, stream>>>(P, batch, pooled);
    final_logits<<<1, 64, 0, stream>>>(pooled, Wl, bl, outp);
}

// Round 9
// 355.228 us; speedup vs baseline: 1.4195x; 1.0076x over previous
//
#include <hip/hip_runtime.h>
#include <math.h>

#define N_NODES 50000
#define N_EDGES 800000
#define F_IN    86
#define H_DIM   128
#define ED_DIM  16
#define C_CLS   18
#define G_GRAPHS 64
#define NEG_SLOPE 0.2f
#define SCAN_BLOCKS ((N_NODES + 255) / 256)   // 196

typedef _Float16 h2v   __attribute__((ext_vector_type(2)));
typedef _Float16 half8 __attribute__((ext_vector_type(8)));
typedef float    f4v   __attribute__((ext_vector_type(4)));

__device__ __forceinline__ void atomicMaxFloat(float* addr, float val) {
    if (val >= 0.0f) atomicMax((int*)addr, __float_as_int(val));
    else             atomicMin((unsigned int*)addr, __float_as_uint(val));
}

// zero cnt (blocks 0..SCAN_BLOCKS-1); ve1/ve2 + zero pooled (block SCAN_BLOCKS)
__global__ void prep(int* __restrict__ cnt, float* __restrict__ pooled,
                     const float* __restrict__ We1, const float* __restrict__ ae1,
                     const float* __restrict__ We2, const float* __restrict__ ae2,
                     float* __restrict__ ve1, float* __restrict__ ve2) {
    int b = blockIdx.x, t = threadIdx.x;
    if (b < SCAN_BLOCKS) {
        int i = b * 256 + t;
        if (i < N_NODES) cnt[i] = 0;
    } else {
        if (t < ED_DIM) {
            float s = 0.f;
            for (int h = 0; h < H_DIM; ++h) s += We1[t * H_DIM + h] * ae1[h];
            ve1[t] = s;
        } else if (t < 2 * ED_DIM) {
            int j = t - ED_DIM;
            float s = 0.f;
            for (int h = 0; h < H_DIM; ++h) s += We2[j * H_DIM + h] * ae2[h];
            ve2[j] = s;
        }
        for (int i = t; i < G_GRAPHS * H_DIM; i += 256) pooled[i] = 0.f;
    }
}

// histogram + per-edge rank (the atomicAdd return is the edge's slot in its row)
__global__ void hist_rank(const int* __restrict__ dst, int* __restrict__ cnt,
                          unsigned short* __restrict__ rank) {
    int e = blockIdx.x * blockDim.x + threadIdx.x;
    if (e < N_EDGES) {
        int r = atomicAdd(&cnt[dst[e]], 1);
        rank[e] = (unsigned short)r;
    }
}

// per-block inclusive scan -> excl (within-block exclusive) + block sums
__global__ void scan1(const int* __restrict__ cnt, int* __restrict__ excl,
                      int* __restrict__ bsum) {
    __shared__ int s[256];
    int tid = threadIdx.x;
    int i = blockIdx.x * 256 + tid;
    int v = (i < N_NODES) ? cnt[i] : 0;
    s[tid] = v;
    __syncthreads();
    for (int o = 1; o < 256; o <<= 1) {
        int t = (tid >= o) ? s[tid - o] : 0;
        __syncthreads();
        s[tid] += t;
        __syncthreads();
    }
    if (i < N_NODES) excl[i] = s[tid] - v;
    if (tid == 255) bsum[blockIdx.x] = s[255];
}

// merged scan2+scan3: every block scans the 196 block sums in LDS (cheap,
// redundant) and writes its slice of row_ptr.
__global__ void scan23(const int* __restrict__ excl, const int* __restrict__ bsum,
                       int* __restrict__ row_ptr) {
    __shared__ int s[256];
    int tid = threadIdx.x;
    int v = (tid < SCAN_BLOCKS) ? bsum[tid] : 0;
    s[tid] = v;
    __syncthreads();
    for (int o = 1; o < 256; o <<= 1) {
        int t = (tid >= o) ? s[tid - o] : 0;
        __syncthreads();
        s[tid] += t;
        __syncthreads();
    }
    int boff = s[blockIdx.x] - bsum[blockIdx.x];   // exclusive prefix of this block
    int i = blockIdx.x * 256 + tid;
    if (i < N_NODES) row_ptr[i] = excl[i] + boff;
    if (i == 0) row_ptr[N_NODES] = N_EDGES;
}

// atomic-free scatter: pos = row_ptr[dst] + rank. All loads sequential or
// L2-cached; stores fire-and-forget; 4 independent edges per thread.
__global__ void scatter_plain(const int* __restrict__ src, const int* __restrict__ dst,
                              const float* __restrict__ ea,
                              const float* __restrict__ ve1, const float* __restrict__ ve2,
                              const int* __restrict__ row_ptr,
                              const unsigned short* __restrict__ rank,
                              int2* __restrict__ perm) {
    int base = blockIdx.x * 1024 + threadIdx.x;
#pragma unroll
    for (int u = 0; u < 4; ++u) {
        int e = base + u * 256;
        if (e >= N_EDGES) continue;
        int d = dst[e];
        int pos = row_ptr[d] + rank[e];
        const float4* p = (const float4*)(ea + (size_t)e * ED_DIM);
        float4 v0 = p[0], v1 = p[1], v2 = p[2], v3 = p[3];
        float s1 = v0.x*ve1[0] + v0.y*ve1[1] + v0.z*ve1[2] + v0.w*ve1[3]
                 + v1.x*ve1[4] + v1.y*ve1[5] + v1.z*ve1[6] + v1.w*ve1[7]
                 + v2.x*ve1[8] + v2.y*ve1[9] + v2.z*ve1[10] + v2.w*ve1[11]
                 + v3.x*ve1[12] + v3.y*ve1[13] + v3.z*ve1[14] + v3.w*ve1[15];
        float s2 = v0.x*ve2[0] + v0.y*ve2[1] + v0.z*ve2[2] + v0.w*ve2[3]
                 + v1.x*ve2[4] + v1.y*ve2[5] + v1.z*ve2[6] + v1.w*ve2[7]
                 + v2.x*ve2[8] + v2.y*ve2[9] + v2.z*ve2[10] + v2.w*ve2[11]
                 + v3.x*ve2[12] + v3.y*ve2[13] + v3.z*ve2[14] + v3.w*ve2[15];
        h2v dv;
        dv.x = (_Float16)s1;
        dv.y = (_Float16)s2;
        perm[pos] = make_int2(src[e], __builtin_bit_cast(int, dv));
    }
}

// conv1 GEMM + fused node dots. h = fp16(x @ W1), K=86 padded to 96.
#define KP1 104
__global__ __launch_bounds__(256)
void gemm1(const float* __restrict__ in, const float* __restrict__ W,
           const float* __restrict__ a_s, const float* __restrict__ a_d,
           _Float16* __restrict__ hout, float* __restrict__ hs, float* __restrict__ hd) {
    __shared__ __attribute__((aligned(16))) _Float16 Asm[64 * KP1];
    __shared__ __attribute__((aligned(16))) _Float16 Bsm[128 * KP1];
    __shared__ float sdots[64][2][2];
    int tid = threadIdx.x;
    int n0 = blockIdx.x * 64;

    const float2* in2 = (const float2*)(in + (size_t)n0 * F_IN);
    for (int idx = tid; idx < 64 * (F_IN / 2); idx += 256) {
        int r = idx / (F_IN / 2), k2 = idx - r * (F_IN / 2);
        float2 v = (n0 + r < N_NODES) ? in2[idx] : make_float2(0.f, 0.f);
        Asm[r * KP1 + 2 * k2]     = (_Float16)v.x;
        Asm[r * KP1 + 2 * k2 + 1] = (_Float16)v.y;
    }
    for (int idx = tid; idx < 64 * (96 - F_IN); idx += 256) {
        int r = idx / (96 - F_IN), k = F_IN + idx - r * (96 - F_IN);
        Asm[r * KP1 + k] = (_Float16)0.f;
    }
    const float4* W4 = (const float4*)W;
    for (int idx = tid; idx < F_IN * 32; idx += 256) {
        float4 v = W4[idx];
        int k = idx >> 5, n = (idx & 31) * 4;
        Bsm[(n + 0) * KP1 + k] = (_Float16)v.x;
        Bsm[(n + 1) * KP1 + k] = (_Float16)v.y;
        Bsm[(n + 2) * KP1 + k] = (_Float16)v.z;
        Bsm[(n + 3) * KP1 + k] = (_Float16)v.w;
    }
    for (int idx = tid; idx < 128 * (96 - F_IN); idx += 256) {
        int n = idx / (96 - F_IN), k = F_IN + idx - n * (96 - F_IN);
        Bsm[n * KP1 + k] = (_Float16)0.f;
    }
    __syncthreads();

    int wave = tid >> 6, lane = tid & 63;
    int wm = (wave & 1) * 32, wn = (wave >> 1) * 64;
    int m16 = lane & 15, quad = lane >> 4;

    f4v acc[2][4];
#pragma unroll
    for (int t = 0; t < 2; ++t)
#pragma unroll
        for (int c = 0; c < 4; ++c) acc[t][c] = (f4v){0.f, 0.f, 0.f, 0.f};

#pragma unroll
    for (int kk = 0; kk < 96 / 32; ++kk) {
        int koff = kk * 32 + quad * 8;
        half8 a0 = *(const half8*)&Asm[(wm + m16) * KP1 + koff];
        half8 a1 = *(const half8*)&Asm[(wm + 16 + m16) * KP1 + koff];
#pragma unroll
        for (int c = 0; c < 4; ++c) {
            half8 b = *(const half8*)&Bsm[(wn + c * 16 + m16) * KP1 + koff];
            acc[0][c] = __builtin_amdgcn_mfma_f32_16x16x32_f16(a0, b, acc[0][c], 0, 0, 0);
            acc[1][c] = __builtin_amdgcn_mfma_f32_16x16x32_f16(a1, b, acc[1][c], 0, 0, 0);
        }
    }

    float asv[4], adv[4];
#pragma unroll
    for (int c = 0; c < 4; ++c) {
        asv[c] = a_s[wn + c * 16 + m16];
        adv[c] = a_d[wn + c * 16 + m16];
    }
#pragma unroll
    for (int t = 0; t < 2; ++t)
#pragma unroll
        for (int r = 0; r < 4; ++r) {
            float ps = 0.f, pd = 0.f;
#pragma unroll
            for (int c = 0; c < 4; ++c) {
                float v = acc[t][c][r];
                ps += v * asv[c];
                pd += v * adv[c];
            }
#pragma unroll
            for (int o = 1; o < 16; o <<= 1) {
                ps += __shfl_xor(ps, o);
                pd += __shfl_xor(pd, o);
            }
            if (m16 == 0) {
                int row = wm + t * 16 + quad * 4 + r;
                sdots[row][wn >> 6][0] = ps;
                sdots[row][wn >> 6][1] = pd;
            }
        }
#pragma unroll
    for (int t = 0; t < 2; ++t)
#pragma unroll
        for (int c = 0; c < 4; ++c)
#pragma unroll
            for (int r = 0; r < 4; ++r) {
                int row = n0 + wm + t * 16 + quad * 4 + r;
                if (row < N_NODES)
                    hout[(size_t)row * H_DIM + wn + c * 16 + m16] = (_Float16)acc[t][c][r];
            }
    __syncthreads();
    if (tid < 64) {
        int row = n0 + tid;
        if (row < N_NODES) {
            hs[row] = sdots[tid][0][0] + sdots[tid][1][0];
            hd[row] = sdots[tid][0][1] + sdots[tid][1][1];
        }
    }
}

// conv2 GEMM + fused node dots. fp16 input, K=128.
#define KP2 136
__global__ __launch_bounds__(256)
void gemm2(const _Float16* __restrict__ in, const float* __restrict__ W,
           const float* __restrict__ a_s, const float* __restrict__ a_d,
           _Float16* __restrict__ hout, float* __restrict__ hs, float* __restrict__ hd) {
    __shared__ __attribute__((aligned(16))) _Float16 Asm[64 * KP2];
    __shared__ __attribute__((aligned(16))) _Float16 Bsm[128 * KP2];
    __shared__ float sdots[64][2][2];
    int tid = threadIdx.x;
    int n0 = blockIdx.x * 64;

    const half8* in8 = (const half8*)(in + (size_t)n0 * H_DIM);
    for (int idx = tid; idx < 64 * 16; idx += 256) {
        int r = idx >> 4, k8 = idx & 15;
        half8 v = (n0 + r < N_NODES) ? in8[idx]
                                     : (half8){0, 0, 0, 0, 0, 0, 0, 0};
        *(half8*)&Asm[r * KP2 + k8 * 8] = v;
    }
    const float4* W4 = (const float4*)W;
    for (int idx = tid; idx < 128 * 32; idx += 256) {
        float4 v = W4[idx];
        int k = idx >> 5, n = (idx & 31) * 4;
        Bsm[(n + 0) * KP2 + k] = (_Float16)v.x;
        Bsm[(n + 1) * KP2 + k] = (_Float16)v.y;
        Bsm[(n + 2) * KP2 + k] = (_Float16)v.z;
        Bsm[(n + 3) * KP2 + k] = (_Float16)v.w;
    }
    __syncthreads();

    int wave = tid >> 6, lane = tid & 63;
    int wm = (wave & 1) * 32, wn = (wave >> 1) * 64;
    int m16 = lane & 15, quad = lane >> 4;

    f4v acc[2][4];
#pragma unroll
    for (int t = 0; t < 2; ++t)
#pragma unroll
        for (int c = 0; c < 4; ++c) acc[t][c] = (f4v){0.f, 0.f, 0.f, 0.f};

#pragma unroll
    for (int kk = 0; kk < 128 / 32; ++kk) {
        int koff = kk * 32 + quad * 8;
        half8 a0 = *(const half8*)&Asm[(wm + m16) * KP2 + koff];
        half8 a1 = *(const half8*)&Asm[(wm + 16 + m16) * KP2 + koff];
#pragma unroll
        for (int c = 0; c < 4; ++c) {
            half8 b = *(const half8*)&Bsm[(wn + c * 16 + m16) * KP2 + koff];
            acc[0][c] = __builtin_amdgcn_mfma_f32_16x16x32_f16(a0, b, acc[0][c], 0, 0, 0);
            acc[1][c] = __builtin_amdgcn_mfma_f32_16x16x32_f16(a1, b, acc[1][c], 0, 0, 0);
        }
    }

    float asv[4], adv[4];
#pragma unroll
    for (int c = 0; c < 4; ++c) {
        asv[c] = a_s[wn + c * 16 + m16];
        adv[c] = a_d[wn + c * 16 + m16];
    }
#pragma unroll
    for (int t = 0; t < 2; ++t)
#pragma unroll
        for (int r = 0; r < 4; ++r) {
            float ps = 0.f, pd = 0.f;
#pragma unroll
            for (int c = 0; c < 4; ++c) {
                float v = acc[t][c][r];
                ps += v * asv[c];
                pd += v * adv[c];
            }
#pragma unroll
            for (int o = 1; o < 16; o <<= 1) {
                ps += __shfl_xor(ps, o);
                pd += __shfl_xor(pd, o);
            }
            if (m16 == 0) {
                int row = wm + t * 16 + quad * 4 + r;
                sdots[row][wn >> 6][0] = ps;
                sdots[row][wn >> 6][1] = pd;
            }
        }
#pragma unroll
    for (int t = 0; t < 2; ++t)
#pragma unroll
        for (int c = 0; c < 4; ++c)
#pragma unroll
            for (int r = 0; r < 4; ++r) {
                int row = n0 + wm + t * 16 + quad * 4 + r;
                if (row < N_NODES)
                    hout[(size_t)row * H_DIM + wn + c * 16 + m16] = (_Float16)acc[t][c][r];
            }
    __syncthreads();
    if (tid < 64) {
        int row = n0 + tid;
        if (row < N_NODES) {
            hs[row] = sdots[tid][0][0] + sdots[tid][1][0];
            hd[row] = sdots[tid][0][1] + sdots[tid][1][1];
        }
    }
}

// One wave per dst node, single-pass softmax (|alpha| small; exp w/o max-sub).
// 8 edges per inner iter: quad q handles edges jj*8+q and jj*8+4+q — two
// independent 16 B gathers in flight per lane (memory-level parallelism).
template<int DOT>
__global__ void gat_node(const int* __restrict__ row_ptr, const int2* __restrict__ perm,
                         const float* __restrict__ hs, const float* __restrict__ hd,
                         const _Float16* __restrict__ h, const float* __restrict__ bias,
                         _Float16* __restrict__ out) {
    int n = blockIdx.x * 4 + (threadIdx.x >> 6);
    int lane = threadIdx.x & 63;
    if (n >= N_NODES) return;
    int q = lane >> 4, m = lane & 15;
    int r0 = row_ptr[n], r1 = row_ptr[n + 1];
    float hdn = hd[n];

    float acc[8];
#pragma unroll
    for (int k = 0; k < 8; ++k) acc[k] = 0.f;
    float denl = 0.f;

    for (int c = r0; c < r1; c += 64) {
        int i = c + lane;
        float w = 0.f;
        int s = 0;
        if (i < r1) {
            int2 p = perm[i];
            s = p.x;
            h2v dv = __builtin_bit_cast(h2v, p.y);
            float dotv = (DOT == 1) ? (float)dv.x : (float)dv.y;
            float t = hs[s] + hdn + dotv;
            t = (t > 0.f) ? t : NEG_SLOPE * t;
            w = __expf(t);
        }
        denl += w;
        int lim = min(64, r1 - c);
        int njj = (lim + 7) >> 3;
        for (int jj = 0; jj < njj; ++jj) {
            int j1 = (jj << 3) + q;          // w==0 beyond lim -> contributes 0
            int j2 = j1 + 4;
            float w1 = __shfl(w, j1);
            int   s1 = __shfl(s, j1);
            float w2 = __shfl(w, j2);
            int   s2 = __shfl(s, j2);
            half8 v1 = *(const half8*)&h[(size_t)s1 * H_DIM + m * 8];
            half8 v2 = *(const half8*)&h[(size_t)s2 * H_DIM + m * 8];
#pragma unroll
            for (int k = 0; k < 8; ++k) acc[k] += w1 * (float)v1[k];
#pragma unroll
            for (int k = 0; k < 8; ++k) acc[k] += w2 * (float)v2[k];
        }
    }
#pragma unroll
    for (int k = 0; k < 8; ++k) {
        acc[k] += __shfl_xor(acc[k], 16);
        acc[k] += __shfl_xor(acc[k], 32);
    }
    float den = denl;
#pragma unroll
    for (int o = 32; o > 0; o >>= 1) den += __shfl_xor(den, o);
    float inv = 1.f / fmaxf(den, 1e-16f);

    if (q == 0) {
        float4 b0 = ((const float4*)bias)[2 * m];
        float4 b1 = ((const float4*)bias)[2 * m + 1];
        half8 ov;
        ov[0] = (_Float16)fmaxf(acc[0] * inv + b0.x, 0.f);
        ov[1] = (_Float16)fmaxf(acc[1] * inv + b0.y, 0.f);
        ov[2] = (_Float16)fmaxf(acc[2] * inv + b0.z, 0.f);
        ov[3] = (_Float16)fmaxf(acc[3] * inv + b0.w, 0.f);
        ov[4] = (_Float16)fmaxf(acc[4] * inv + b1.x, 0.f);
        ov[5] = (_Float16)fmaxf(acc[5] * inv + b1.y, 0.f);
        ov[6] = (_Float16)fmaxf(acc[6] * inv + b1.z, 0.f);
        ov[7] = (_Float16)fmaxf(acc[7] * inv + b1.w, 0.f);
        *(half8*)&out[(size_t)n * H_DIM + m * 8] = ov;
    }
}

// pooled[g,t] = max over nodes of P[n,t]; P>=0, pooled pre-zeroed
__global__ void pool_max(const _Float16* __restrict__ P,
                         const int* __restrict__ batch, float* __restrict__ pooled) {
    int t = threadIdx.x;  // 128
    int n0 = blockIdx.x * 64;
    int n1 = min(n0 + 64, N_NODES);
    if (n0 >= N_NODES) return;
    int cur = batch[n0];
    float acc = 0.f;
    for (int n = n0; n < n1; ++n) {
        int g = batch[n];
        if (g != cur) {
            atomicMaxFloat(&pooled[cur * H_DIM + t], acc);
            acc = 0.f;
            cur = g;
        }
        acc = fmaxf(acc, (float)P[(size_t)n * H_DIM + t]);
    }
    atomicMaxFloat(&pooled[cur * H_DIM + t], acc);
}

__global__ void final_logits(const float* __restrict__ pooled, const float* __restrict__ Wl,
                             const float* __restrict__ bl, float* __restrict__ outp) {
    int g = threadIdx.x;  // 64
    if (g >= G_GRAPHS) return;
    float lg[C_CLS];
#pragma unroll
    for (int c = 0; c < C_CLS; ++c) lg[c] = bl[c];
    for (int k = 0; k < H_DIM; ++k) {
        float v = pooled[g * H_DIM + k];
#pragma unroll
        for (int c = 0; c < C_CLS; ++c) lg[c] += v * Wl[k * C_CLS + c];
    }
    float mx = lg[0];
#pragma unroll
    for (int c = 1; c < C_CLS; ++c) mx = fmaxf(mx, lg[c]);
    float se = 0.f;
#pragma unroll
    for (int c = 0; c < C_CLS; ++c) se += expf(lg[c] - mx);
    float lse = logf(se);
#pragma unroll
    for (int c = 0; c < C_CLS; ++c) outp[g * C_CLS + c] = lg[c] - mx - lse;
}

extern "C" void kernel_launch(void* const* d_in, const int* in_sizes, int n_in,
                              void* d_out, int out_size, void* d_ws, size_t ws_size,
                              hipStream_t stream) {
    const float* x     = (const float*)d_in[0];
    const int*   eidx  = (const int*)d_in[1];
    const float* ea    = (const float*)d_in[2];
    const int*   batch = (const int*)d_in[3];
    const float* W1  = (const float*)d_in[4];
    const float* We1 = (const float*)d_in[5];
    const float* as1 = (const float*)d_in[6];
    const float* ad1 = (const float*)d_in[7];
    const float* ae1 = (const float*)d_in[8];
    const float* b1  = (const float*)d_in[9];
    const float* W2  = (const float*)d_in[10];
    const float* We2 = (const float*)d_in[11];
    const float* as2 = (const float*)d_in[12];
    const float* ad2 = (const float*)d_in[13];
    const float* ae2 = (const float*)d_in[14];
    const float* b2  = (const float*)d_in[15];
    const float* Wl  = (const float*)d_in[16];
    const float* bl  = (const float*)d_in[17];
    float* outp = (float*)d_out;

    const int* src = eidx;
    const int* dst = eidx + N_EDGES;

    char* wsb = (char*)d_ws;
    size_t off = 0;
    auto alloc = [&](size_t bytes) { char* p = wsb + off; off += (bytes + 255) & ~(size_t)255; return p; };
    _Float16* h    = (_Float16*)alloc((size_t)N_NODES * H_DIM * 2);
    _Float16* A2   = (_Float16*)alloc((size_t)N_NODES * H_DIM * 2);
    _Float16* P    = (_Float16*)alloc((size_t)N_NODES * H_DIM * 2);
    int2*  perm    = (int2*)alloc((size_t)N_EDGES * 8);
    unsigned short* rank = (unsigned short*)alloc((size_t)N_EDGES * 2);
    float* hs      = (float*)alloc(N_NODES * 4);
    float* hd      = (float*)alloc(N_NODES * 4);
    int*   row_ptr = (int*)alloc((N_NODES + 1) * 4);
    int*   cnt     = (int*)alloc(N_NODES * 4);
    int*   excl    = (int*)alloc(N_NODES * 4);
    int*   bsum    = (int*)alloc(SCAN_BLOCKS * 4);
    float* pooled  = (float*)alloc(G_GRAPHS * H_DIM * 4);
    float* ve1     = (float*)alloc(16 * 4);
    float* ve2     = (float*)alloc(16 * 4);

    const int EB = (N_EDGES + 255) / 256;
    const int NB4 = (N_NODES + 3) / 4;
    const int GB = (N_NODES + 63) / 64;

    // prep + CSR build (rank-trick: scatter has no atomics)
    prep<<<SCAN_BLOCKS + 1, 256, 0, stream>>>(cnt, pooled, We1, ae1, We2, ae2, ve1, ve2);
    hist_rank<<<EB, 256, 0, stream>>>(dst, cnt, rank);
    scan1<<<SCAN_BLOCKS, 256, 0, stream>>>(cnt, excl, bsum);
    scan23<<<SCAN_BLOCKS, 256, 0, stream>>>(excl, bsum, row_ptr);
    scatter_plain<<<(N_EDGES + 1023) / 1024, 256, 0, stream>>>(src, dst, ea, ve1, ve2,
                                                               row_ptr, rank, perm);

    // ---- conv1 ----
    gemm1<<<GB, 256, 0, stream>>>(x, W1, as1, ad1, h, hs, hd);
    gat_node<1><<<NB4, 256, 0, stream>>>(row_ptr, perm, hs, hd, h, b1, A2);

    // ---- conv2 ----
    gemm2<<<GB, 256, 0, stream>>>(A2, W2, as2, ad2, h, hs, hd);
    gat_node<2><<<NB4, 256, 0, stream>>>(row_ptr, perm, hs, hd, h, b2, P);

    // ---- pool + classifier ----
    pool_max<<<GB, 128, 0, stream>>>(P, batch, pooled);
    final_logits<<<1, 64, 0, stream>>>(pooled, Wl, bl, outp);
}

// Round 10
// 342.237 us; speedup vs baseline: 1.4733x; 1.0380x over previous
//
#include <hip/hip_runtime.h>
#include <math.h>

#define N_NODES 50000
#define N_EDGES 800000
#define F_IN    86
#define H_DIM   128
#define ED_DIM  16
#define C_CLS   18
#define G_GRAPHS 64
#define NEG_SLOPE 0.2f
#define SCAN_BLOCKS ((N_NODES + 255) / 256)   // 196

typedef _Float16 h2v   __attribute__((ext_vector_type(2)));
typedef _Float16 half8 __attribute__((ext_vector_type(8)));
typedef float    f4v   __attribute__((ext_vector_type(4)));

__device__ __forceinline__ void atomicMaxFloat(float* addr, float val) {
    if (val >= 0.0f) atomicMax((int*)addr, __float_as_int(val));
    else             atomicMin((unsigned int*)addr, __float_as_uint(val));
}

// zero cnt (blocks 0..SCAN_BLOCKS-1); ve1/ve2 + zero pooled (block SCAN_BLOCKS)
__global__ void prep(int* __restrict__ cnt, float* __restrict__ pooled,
                     const float* __restrict__ We1, const float* __restrict__ ae1,
                     const float* __restrict__ We2, const float* __restrict__ ae2,
                     float* __restrict__ ve1, float* __restrict__ ve2) {
    int b = blockIdx.x, t = threadIdx.x;
    if (b < SCAN_BLOCKS) {
        int i = b * 256 + t;
        if (i < N_NODES) cnt[i] = 0;
    } else {
        if (t < ED_DIM) {
            float s = 0.f;
            for (int h = 0; h < H_DIM; ++h) s += We1[t * H_DIM + h] * ae1[h];
            ve1[t] = s;
        } else if (t < 2 * ED_DIM) {
            int j = t - ED_DIM;
            float s = 0.f;
            for (int h = 0; h < H_DIM; ++h) s += We2[j * H_DIM + h] * ae2[h];
            ve2[j] = s;
        }
        for (int i = t; i < G_GRAPHS * H_DIM; i += 256) pooled[i] = 0.f;
    }
}

// histogram + per-edge rank + edge-attr dots (sequential ea read hides
// behind the atomic latency; dotp is a 4 B sequential write per edge)
__global__ void hist_rank_dots(const int* __restrict__ dst, int* __restrict__ cnt,
                               unsigned short* __restrict__ rank,
                               const float* __restrict__ ea,
                               const float* __restrict__ ve1, const float* __restrict__ ve2,
                               unsigned int* __restrict__ dotp) {
    int e = blockIdx.x * blockDim.x + threadIdx.x;
    if (e >= N_EDGES) return;
    int r = atomicAdd(&cnt[dst[e]], 1);
    rank[e] = (unsigned short)r;
    const float4* p = (const float4*)(ea + (size_t)e * ED_DIM);
    float4 v0 = p[0], v1 = p[1], v2 = p[2], v3 = p[3];
    float s1 = v0.x*ve1[0] + v0.y*ve1[1] + v0.z*ve1[2] + v0.w*ve1[3]
             + v1.x*ve1[4] + v1.y*ve1[5] + v1.z*ve1[6] + v1.w*ve1[7]
             + v2.x*ve1[8] + v2.y*ve1[9] + v2.z*ve1[10] + v2.w*ve1[11]
             + v3.x*ve1[12] + v3.y*ve1[13] + v3.z*ve1[14] + v3.w*ve1[15];
    float s2 = v0.x*ve2[0] + v0.y*ve2[1] + v0.z*ve2[2] + v0.w*ve2[3]
             + v1.x*ve2[4] + v1.y*ve2[5] + v1.z*ve2[6] + v1.w*ve2[7]
             + v2.x*ve2[8] + v2.y*ve2[9] + v2.z*ve2[10] + v2.w*ve2[11]
             + v3.x*ve2[12] + v3.y*ve2[13] + v3.z*ve2[14] + v3.w*ve2[15];
    h2v dv;
    dv.x = (_Float16)s1;
    dv.y = (_Float16)s2;
    dotp[e] = __builtin_bit_cast(unsigned int, dv);
}

// per-block inclusive scan -> excl (within-block exclusive) + block sums
__global__ void scan1(const int* __restrict__ cnt, int* __restrict__ excl,
                      int* __restrict__ bsum) {
    __shared__ int s[256];
    int tid = threadIdx.x;
    int i = blockIdx.x * 256 + tid;
    int v = (i < N_NODES) ? cnt[i] : 0;
    s[tid] = v;
    __syncthreads();
    for (int o = 1; o < 256; o <<= 1) {
        int t = (tid >= o) ? s[tid - o] : 0;
        __syncthreads();
        s[tid] += t;
        __syncthreads();
    }
    if (i < N_NODES) excl[i] = s[tid] - v;
    if (tid == 255) bsum[blockIdx.x] = s[255];
}

// merged scan2+scan3: every block scans the 196 block sums in LDS and
// writes its slice of row_ptr.
__global__ void scan23(const int* __restrict__ excl, const int* __restrict__ bsum,
                       int* __restrict__ row_ptr) {
    __shared__ int s[256];
    int tid = threadIdx.x;
    int v = (tid < SCAN_BLOCKS) ? bsum[tid] : 0;
    s[tid] = v;
    __syncthreads();
    for (int o = 1; o < 256; o <<= 1) {
        int t = (tid >= o) ? s[tid - o] : 0;
        __syncthreads();
        s[tid] += t;
        __syncthreads();
    }
    int boff = s[blockIdx.x] - bsum[blockIdx.x];
    int i = blockIdx.x * 256 + tid;
    if (i < N_NODES) row_ptr[i] = excl[i] + boff;
    if (i == 0) row_ptr[N_NODES] = N_EDGES;
}

// lite scatter: 1 edge/thread (max TLP for the dst->row_ptr->store chain);
// all reads coalesced 14 B/edge, one random 8 B store.
__global__ void scatter_lite(const int* __restrict__ src, const int* __restrict__ dst,
                             const int* __restrict__ row_ptr,
                             const unsigned short* __restrict__ rank,
                             const unsigned int* __restrict__ dotp,
                             int2* __restrict__ perm) {
    int e = blockIdx.x * blockDim.x + threadIdx.x;
    if (e >= N_EDGES) return;
    int pos = row_ptr[dst[e]] + rank[e];
    perm[pos] = make_int2(src[e], (int)dotp[e]);
}

// conv1 GEMM + fused node dots. h = fp16(x @ W1), K=86 padded to 96.
#define KP1 104
__global__ __launch_bounds__(256)
void gemm1(const float* __restrict__ in, const float* __restrict__ W,
           const float* __restrict__ a_s, const float* __restrict__ a_d,
           _Float16* __restrict__ hout, float* __restrict__ hs, float* __restrict__ hd) {
    __shared__ __attribute__((aligned(16))) _Float16 Asm[64 * KP1];
    __shared__ __attribute__((aligned(16))) _Float16 Bsm[128 * KP1];
    __shared__ float sdots[64][2][2];
    int tid = threadIdx.x;
    int n0 = blockIdx.x * 64;

    const float2* in2 = (const float2*)(in + (size_t)n0 * F_IN);
    for (int idx = tid; idx < 64 * (F_IN / 2); idx += 256) {
        int r = idx / (F_IN / 2), k2 = idx - r * (F_IN / 2);
        float2 v = (n0 + r < N_NODES) ? in2[idx] : make_float2(0.f, 0.f);
        Asm[r * KP1 + 2 * k2]     = (_Float16)v.x;
        Asm[r * KP1 + 2 * k2 + 1] = (_Float16)v.y;
    }
    for (int idx = tid; idx < 64 * (96 - F_IN); idx += 256) {
        int r = idx / (96 - F_IN), k = F_IN + idx - r * (96 - F_IN);
        Asm[r * KP1 + k] = (_Float16)0.f;
    }
    const float4* W4 = (const float4*)W;
    for (int idx = tid; idx < F_IN * 32; idx += 256) {
        float4 v = W4[idx];
        int k = idx >> 5, n = (idx & 31) * 4;
        Bsm[(n + 0) * KP1 + k] = (_Float16)v.x;
        Bsm[(n + 1) * KP1 + k] = (_Float16)v.y;
        Bsm[(n + 2) * KP1 + k] = (_Float16)v.z;
        Bsm[(n + 3) * KP1 + k] = (_Float16)v.w;
    }
    for (int idx = tid; idx < 128 * (96 - F_IN); idx += 256) {
        int n = idx / (96 - F_IN), k = F_IN + idx - n * (96 - F_IN);
        Bsm[n * KP1 + k] = (_Float16)0.f;
    }
    __syncthreads();

    int wave = tid >> 6, lane = tid & 63;
    int wm = (wave & 1) * 32, wn = (wave >> 1) * 64;
    int m16 = lane & 15, quad = lane >> 4;

    f4v acc[2][4];
#pragma unroll
    for (int t = 0; t < 2; ++t)
#pragma unroll
        for (int c = 0; c < 4; ++c) acc[t][c] = (f4v){0.f, 0.f, 0.f, 0.f};

#pragma unroll
    for (int kk = 0; kk < 96 / 32; ++kk) {
        int koff = kk * 32 + quad * 8;
        half8 a0 = *(const half8*)&Asm[(wm + m16) * KP1 + koff];
        half8 a1 = *(const half8*)&Asm[(wm + 16 + m16) * KP1 + koff];
#pragma unroll
        for (int c = 0; c < 4; ++c) {
            half8 b = *(const half8*)&Bsm[(wn + c * 16 + m16) * KP1 + koff];
            acc[0][c] = __builtin_amdgcn_mfma_f32_16x16x32_f16(a0, b, acc[0][c], 0, 0, 0);
            acc[1][c] = __builtin_amdgcn_mfma_f32_16x16x32_f16(a1, b, acc[1][c], 0, 0, 0);
        }
    }

    float asv[4], adv[4];
#pragma unroll
    for (int c = 0; c < 4; ++c) {
        asv[c] = a_s[wn + c * 16 + m16];
        adv[c] = a_d[wn + c * 16 + m16];
    }
#pragma unroll
    for (int t = 0; t < 2; ++t)
#pragma unroll
        for (int r = 0; r < 4; ++r) {
            float ps = 0.f, pd = 0.f;
#pragma unroll
            for (int c = 0; c < 4; ++c) {
                float v = acc[t][c][r];
                ps += v * asv[c];
                pd += v * adv[c];
            }
#pragma unroll
            for (int o = 1; o < 16; o <<= 1) {
                ps += __shfl_xor(ps, o);
                pd += __shfl_xor(pd, o);
            }
            if (m16 == 0) {
                int row = wm + t * 16 + quad * 4 + r;
                sdots[row][wn >> 6][0] = ps;
                sdots[row][wn >> 6][1] = pd;
            }
        }
#pragma unroll
    for (int t = 0; t < 2; ++t)
#pragma unroll
        for (int c = 0; c < 4; ++c)
#pragma unroll
            for (int r = 0; r < 4; ++r) {
                int row = n0 + wm + t * 16 + quad * 4 + r;
                if (row < N_NODES)
                    hout[(size_t)row * H_DIM + wn + c * 16 + m16] = (_Float16)acc[t][c][r];
            }
    __syncthreads();
    if (tid < 64) {
        int row = n0 + tid;
        if (row < N_NODES) {
            hs[row] = sdots[tid][0][0] + sdots[tid][1][0];
            hd[row] = sdots[tid][0][1] + sdots[tid][1][1];
        }
    }
}

// conv2 GEMM + fused node dots. fp16 input, K=128.
#define KP2 136
__global__ __launch_bounds__(256)
void gemm2(const _Float16* __restrict__ in, const float* __restrict__ W,
           const float* __restrict__ a_s, const float* __restrict__ a_d,
           _Float16* __restrict__ hout, float* __restrict__ hs, float* __restrict__ hd) {
    __shared__ __attribute__((aligned(16))) _Float16 Asm[64 * KP2];
    __shared__ __attribute__((aligned(16))) _Float16 Bsm[128 * KP2];
    __shared__ float sdots[64][2][2];
    int tid = threadIdx.x;
    int n0 = blockIdx.x * 64;

    const half8* in8 = (const half8*)(in + (size_t)n0 * H_DIM);
    for (int idx = tid; idx < 64 * 16; idx += 256) {
        int r = idx >> 4, k8 = idx & 15;
        half8 v = (n0 + r < N_NODES) ? in8[idx]
                                     : (half8){0, 0, 0, 0, 0, 0, 0, 0};
        *(half8*)&Asm[r * KP2 + k8 * 8] = v;
    }
    const float4* W4 = (const float4*)W;
    for (int idx = tid; idx < 128 * 32; idx += 256) {
        float4 v = W4[idx];
        int k = idx >> 5, n = (idx & 31) * 4;
        Bsm[(n + 0) * KP2 + k] = (_Float16)v.x;
        Bsm[(n + 1) * KP2 + k] = (_Float16)v.y;
        Bsm[(n + 2) * KP2 + k] = (_Float16)v.z;
        Bsm[(n + 3) * KP2 + k] = (_Float16)v.w;
    }
    __syncthreads();

    int wave = tid >> 6, lane = tid & 63;
    int wm = (wave & 1) * 32, wn = (wave >> 1) * 64;
    int m16 = lane & 15, quad = lane >> 4;

    f4v acc[2][4];
#pragma unroll
    for (int t = 0; t < 2; ++t)
#pragma unroll
        for (int c = 0; c < 4; ++c) acc[t][c] = (f4v){0.f, 0.f, 0.f, 0.f};

#pragma unroll
    for (int kk = 0; kk < 128 / 32; ++kk) {
        int koff = kk * 32 + quad * 8;
        half8 a0 = *(const half8*)&Asm[(wm + m16) * KP2 + koff];
        half8 a1 = *(const half8*)&Asm[(wm + 16 + m16) * KP2 + koff];
#pragma unroll
        for (int c = 0; c < 4; ++c) {
            half8 b = *(const half8*)&Bsm[(wn + c * 16 + m16) * KP2 + koff];
            acc[0][c] = __builtin_amdgcn_mfma_f32_16x16x32_f16(a0, b, acc[0][c], 0, 0, 0);
            acc[1][c] = __builtin_amdgcn_mfma_f32_16x16x32_f16(a1, b, acc[1][c], 0, 0, 0);
        }
    }

    float asv[4], adv[4];
#pragma unroll
    for (int c = 0; c < 4; ++c) {
        asv[c] = a_s[wn + c * 16 + m16];
        adv[c] = a_d[wn + c * 16 + m16];
    }
#pragma unroll
    for (int t = 0; t < 2; ++t)
#pragma unroll
        for (int r = 0; r < 4; ++r) {
            float ps = 0.f, pd = 0.f;
#pragma unroll
            for (int c = 0; c < 4; ++c) {
                float v = acc[t][c][r];
                ps += v * asv[c];
                pd += v * adv[c];
            }
#pragma unroll
            for (int o = 1; o < 16; o <<= 1) {
                ps += __shfl_xor(ps, o);
                pd += __shfl_xor(pd, o);
            }
            if (m16 == 0) {
                int row = wm + t * 16 + quad * 4 + r;
                sdots[row][wn >> 6][0] = ps;
                sdots[row][wn >> 6][1] = pd;
            }
        }
#pragma unroll
    for (int t = 0; t < 2; ++t)
#pragma unroll
        for (int c = 0; c < 4; ++c)
#pragma unroll
            for (int r = 0; r < 4; ++r) {
                int row = n0 + wm + t * 16 + quad * 4 + r;
                if (row < N_NODES)
                    hout[(size_t)row * H_DIM + wn + c * 16 + m16] = (_Float16)acc[t][c][r];
            }
    __syncthreads();
    if (tid < 64) {
        int row = n0 + tid;
        if (row < N_NODES) {
            hs[row] = sdots[tid][0][0] + sdots[tid][1][0];
            hd[row] = sdots[tid][0][1] + sdots[tid][1][1];
        }
    }
}

// One wave per dst node, single-pass softmax (|alpha| small; exp w/o max-sub).
// 8 edges per inner iter: quad q handles edges jj*8+q and jj*8+4+q.
template<int DOT>
__global__ void gat_node(const int* __restrict__ row_ptr, const int2* __restrict__ perm,
                         const float* __restrict__ hs, const float* __restrict__ hd,
                         const _Float16* __restrict__ h, const float* __restrict__ bias,
                         _Float16* __restrict__ out) {
    int n = blockIdx.x * 4 + (threadIdx.x >> 6);
    int lane = threadIdx.x & 63;
    if (n >= N_NODES) return;
    int q = lane >> 4, m = lane & 15;
    int r0 = row_ptr[n], r1 = row_ptr[n + 1];
    float hdn = hd[n];

    float acc[8];
#pragma unroll
    for (int k = 0; k < 8; ++k) acc[k] = 0.f;
    float denl = 0.f;

    for (int c = r0; c < r1; c += 64) {
        int i = c + lane;
        float w = 0.f;
        int s = 0;
        if (i < r1) {
            int2 p = perm[i];
            s = p.x;
            h2v dv = __builtin_bit_cast(h2v, p.y);
            float dotv = (DOT == 1) ? (float)dv.x : (float)dv.y;
            float t = hs[s] + hdn + dotv;
            t = (t > 0.f) ? t : NEG_SLOPE * t;
            w = __expf(t);
        }
        denl += w;
        int lim = min(64, r1 - c);
        int njj = (lim + 7) >> 3;
        for (int jj = 0; jj < njj; ++jj) {
            int j1 = (jj << 3) + q;
            int j2 = j1 + 4;
            float w1 = __shfl(w, j1);
            int   s1 = __shfl(s, j1);
            float w2 = __shfl(w, j2);
            int   s2 = __shfl(s, j2);
            half8 v1 = *(const half8*)&h[(size_t)s1 * H_DIM + m * 8];
            half8 v2 = *(const half8*)&h[(size_t)s2 * H_DIM + m * 8];
#pragma unroll
            for (int k = 0; k < 8; ++k) acc[k] += w1 * (float)v1[k];
#pragma unroll
            for (int k = 0; k < 8; ++k) acc[k] += w2 * (float)v2[k];
        }
    }
#pragma unroll
    for (int k = 0; k < 8; ++k) {
        acc[k] += __shfl_xor(acc[k], 16);
        acc[k] += __shfl_xor(acc[k], 32);
    }
    float den = denl;
#pragma unroll
    for (int o = 32; o > 0; o >>= 1) den += __shfl_xor(den, o);
    float inv = 1.f / fmaxf(den, 1e-16f);

    if (q == 0) {
        float4 b0 = ((const float4*)bias)[2 * m];
        float4 b1 = ((const float4*)bias)[2 * m + 1];
        half8 ov;
        ov[0] = (_Float16)fmaxf(acc[0] * inv + b0.x, 0.f);
        ov[1] = (_Float16)fmaxf(acc[1] * inv + b0.y, 0.f);
        ov[2] = (_Float16)fmaxf(acc[2] * inv + b0.z, 0.f);
        ov[3] = (_Float16)fmaxf(acc[3] * inv + b0.w, 0.f);
        ov[4] = (_Float16)fmaxf(acc[4] * inv + b1.x, 0.f);
        ov[5] = (_Float16)fmaxf(acc[5] * inv + b1.y, 0.f);
        ov[6] = (_Float16)fmaxf(acc[6] * inv + b1.z, 0.f);
        ov[7] = (_Float16)fmaxf(acc[7] * inv + b1.w, 0.f);
        *(half8*)&out[(size_t)n * H_DIM + m * 8] = ov;
    }
}

// pooled[g,t] = max over nodes of P[n,t]; P>=0, pooled pre-zeroed
__global__ void pool_max(const _Float16* __restrict__ P,
                         const int* __restrict__ batch, float* __restrict__ pooled) {
    int t = threadIdx.x;  // 128
    int n0 = blockIdx.x * 64;
    int n1 = min(n0 + 64, N_NODES);
    if (n0 >= N_NODES) return;
    int cur = batch[n0];
    float acc = 0.f;
    for (int n = n0; n < n1; ++n) {
        int g = batch[n];
        if (g != cur) {
            atomicMaxFloat(&pooled[cur * H_DIM + t], acc);
            acc = 0.f;
            cur = g;
        }
        acc = fmaxf(acc, (float)P[(size_t)n * H_DIM + t]);
    }
    atomicMaxFloat(&pooled[cur * H_DIM + t], acc);
}

__global__ void final_logits(const float* __restrict__ pooled, const float* __restrict__ Wl,
                             const float* __restrict__ bl, float* __restrict__ outp) {
    int g = threadIdx.x;  // 64
    if (g >= G_GRAPHS) return;
    float lg[C_CLS];
#pragma unroll
    for (int c = 0; c < C_CLS; ++c) lg[c] = bl[c];
    for (int k = 0; k < H_DIM; ++k) {
        float v = pooled[g * H_DIM + k];
#pragma unroll
        for (int c = 0; c < C_CLS; ++c) lg[c] += v * Wl[k * C_CLS + c];
    }
    float mx = lg[0];
#pragma unroll
    for (int c = 1; c < C_CLS; ++c) mx = fmaxf(mx, lg[c]);
    float se = 0.f;
#pragma unroll
    for (int c = 0; c < C_CLS; ++c) se += expf(lg[c] - mx);
    float lse = logf(se);
#pragma unroll
    for (int c = 0; c < C_CLS; ++c) outp[g * C_CLS + c] = lg[c] - mx - lse;
}

extern "C" void kernel_launch(void* const* d_in, const int* in_sizes, int n_in,
                              void* d_out, int out_size, void* d_ws, size_t ws_size,
                              hipStream_t stream) {
    const float* x     = (const float*)d_in[0];
    const int*   eidx  = (const int*)d_in[1];
    const float* ea    = (const float*)d_in[2];
    const int*   batch = (const int*)d_in[3];
    const float* W1  = (const float*)d_in[4];
    const float* We1 = (const float*)d_in[5];
    const float* as1 = (const float*)d_in[6];
    const float* ad1 = (const float*)d_in[7];
    const float* ae1 = (const float*)d_in[8];
    const float* b1  = (const float*)d_in[9];
    const float* W2  = (const float*)d_in[10];
    const float* We2 = (const float*)d_in[11];
    const float* as2 = (const float*)d_in[12];
    const float* ad2 = (const float*)d_in[13];
    const float* ae2 = (const float*)d_in[14];
    const float* b2  = (const float*)d_in[15];
    const float* Wl  = (const float*)d_in[16];
    const float* bl  = (const float*)d_in[17];
    float* outp = (float*)d_out;

    const int* src = eidx;
    const int* dst = eidx + N_EDGES;

    char* wsb = (char*)d_ws;
    size_t off = 0;
    auto alloc = [&](size_t bytes) { char* p = wsb + off; off += (bytes + 255) & ~(size_t)255; return p; };
    _Float16* h    = (_Float16*)alloc((size_t)N_NODES * H_DIM * 2);
    _Float16* A2   = (_Float16*)alloc((size_t)N_NODES * H_DIM * 2);
    _Float16* P    = (_Float16*)alloc((size_t)N_NODES * H_DIM * 2);
    int2*  perm    = (int2*)alloc((size_t)N_EDGES * 8);
    unsigned short* rank = (unsigned short*)alloc((size_t)N_EDGES * 2);
    unsigned int* dotp = (unsigned int*)alloc((size_t)N_EDGES * 4);
    float* hs      = (float*)alloc(N_NODES * 4);
    float* hd      = (float*)alloc(N_NODES * 4);
    int*   row_ptr = (int*)alloc((N_NODES + 1) * 4);
    int*   cnt     = (int*)alloc(N_NODES * 4);
    int*   excl    = (int*)alloc(N_NODES * 4);
    int*   bsum    = (int*)alloc(SCAN_BLOCKS * 4);
    float* pooled  = (float*)alloc(G_GRAPHS * H_DIM * 4);
    float* ve1     = (float*)alloc(16 * 4);
    float* ve2     = (float*)alloc(16 * 4);

    const int EB = (N_EDGES + 255) / 256;
    const int NB4 = (N_NODES + 3) / 4;
    const int GB = (N_NODES + 63) / 64;

    // prep + CSR build (rank-trick; dots computed in hist pass; lite scatter)
    prep<<<SCAN_BLOCKS + 1, 256, 0, stream>>>(cnt, pooled, We1, ae1, We2, ae2, ve1, ve2);
    hist_rank_dots<<<EB, 256, 0, stream>>>(dst, cnt, rank, ea, ve1, ve2, dotp);
    scan1<<<SCAN_BLOCKS, 256, 0, stream>>>(cnt, excl, bsum);
    scan23<<<SCAN_BLOCKS, 256, 0, stream>>>(excl, bsum, row_ptr);
    scatter_lite<<<EB, 256, 0, stream>>>(src, dst, row_ptr, rank, dotp, perm);

    // ---- conv1 ----
    gemm1<<<GB, 256, 0, stream>>>(x, W1, as1, ad1, h, hs, hd);
    gat_node<1><<<NB4, 256, 0, stream>>>(row_ptr, perm, hs, hd, h, b1, A2);

    // ---- conv2 ----
    gemm2<<<GB, 256, 0, stream>>>(A2, W2, as2, ad2, h, hs, hd);
    gat_node<2><<<NB4, 256, 0, stream>>>(row_ptr, perm, hs, hd, h, b2, P);

    // ---- pool + classifier ----
    pool_max<<<GB, 128, 0, stream>>>(P, batch, pooled);
    final_logits<<<1, 64, 0, stream>>>(pooled, Wl, bl, outp);
}

// Round 11
// 327.163 us; speedup vs baseline: 1.5412x; 1.0461x over previous
//
#include <hip/hip_runtime.h>
#include <math.h>

#define N_NODES 50000
#define N_EDGES 800000
#define F_IN    86
#define H_DIM   128
#define ED_DIM  16
#define C_CLS   18
#define G_GRAPHS 64
#define NEG_SLOPE 0.2f
#define SCAN_BLOCKS ((N_NODES + 255) / 256)   // 196
#define EB_BLOCKS ((N_EDGES + 255) / 256)     // 3125
#define GB_BLOCKS ((N_NODES + 63) / 64)       // 782

typedef _Float16 h2v   __attribute__((ext_vector_type(2)));
typedef _Float16 half8 __attribute__((ext_vector_type(8)));
typedef float    f4v   __attribute__((ext_vector_type(4)));

__device__ __forceinline__ void atomicMaxFloat(float* addr, float val) {
    if (val >= 0.0f) atomicMax((int*)addr, __float_as_int(val));
    else             atomicMin((unsigned int*)addr, __float_as_uint(val));
}

// zero cnt (blocks 0..SCAN_BLOCKS-1); ve1/ve2 + zero pooled (block SCAN_BLOCKS)
__global__ void prep(int* __restrict__ cnt, float* __restrict__ pooled,
                     const float* __restrict__ We1, const float* __restrict__ ae1,
                     const float* __restrict__ We2, const float* __restrict__ ae2,
                     float* __restrict__ ve1, float* __restrict__ ve2) {
    int b = blockIdx.x, t = threadIdx.x;
    if (b < SCAN_BLOCKS) {
        int i = b * 256 + t;
        if (i < N_NODES) cnt[i] = 0;
    } else {
        if (t < ED_DIM) {
            float s = 0.f;
            for (int h = 0; h < H_DIM; ++h) s += We1[t * H_DIM + h] * ae1[h];
            ve1[t] = s;
        } else if (t < 2 * ED_DIM) {
            int j = t - ED_DIM;
            float s = 0.f;
            for (int h = 0; h < H_DIM; ++h) s += We2[j * H_DIM + h] * ae2[h];
            ve2[j] = s;
        }
        for (int i = t; i < G_GRAPHS * H_DIM; i += 256) pooled[i] = 0.f;
    }
}

// Fused: blocks [0,EB) = histogram+rank+edge-dots; blocks [EB,EB+GB) = conv1
// MFMA GEMM + node dots. Independent work overlapped in one launch.
#define KP1 104
__global__ __launch_bounds__(256)
void hist_gemm1(const int* __restrict__ dst, int* __restrict__ cnt,
                unsigned short* __restrict__ rank,
                const float* __restrict__ ea,
                const float* __restrict__ ve1, const float* __restrict__ ve2,
                unsigned int* __restrict__ dotp,
                const float* __restrict__ in, const float* __restrict__ W,
                const float* __restrict__ a_s, const float* __restrict__ a_d,
                _Float16* __restrict__ hout, float* __restrict__ hs,
                float* __restrict__ hd) {
    if (blockIdx.x < EB_BLOCKS) {
        int e = blockIdx.x * 256 + threadIdx.x;
        if (e >= N_EDGES) return;
        int r = atomicAdd(&cnt[dst[e]], 1);
        rank[e] = (unsigned short)r;
        const float4* p = (const float4*)(ea + (size_t)e * ED_DIM);
        float4 v0 = p[0], v1 = p[1], v2 = p[2], v3 = p[3];
        float s1 = v0.x*ve1[0] + v0.y*ve1[1] + v0.z*ve1[2] + v0.w*ve1[3]
                 + v1.x*ve1[4] + v1.y*ve1[5] + v1.z*ve1[6] + v1.w*ve1[7]
                 + v2.x*ve1[8] + v2.y*ve1[9] + v2.z*ve1[10] + v2.w*ve1[11]
                 + v3.x*ve1[12] + v3.y*ve1[13] + v3.z*ve1[14] + v3.w*ve1[15];
        float s2 = v0.x*ve2[0] + v0.y*ve2[1] + v0.z*ve2[2] + v0.w*ve2[3]
                 + v1.x*ve2[4] + v1.y*ve2[5] + v1.z*ve2[6] + v1.w*ve2[7]
                 + v2.x*ve2[8] + v2.y*ve2[9] + v2.z*ve2[10] + v2.w*ve2[11]
                 + v3.x*ve2[12] + v3.y*ve2[13] + v3.z*ve2[14] + v3.w*ve2[15];
        h2v dv;
        dv.x = (_Float16)s1;
        dv.y = (_Float16)s2;
        dotp[e] = __builtin_bit_cast(unsigned int, dv);
        return;
    }
    // ---- conv1 GEMM branch ----
    __shared__ __attribute__((aligned(16))) _Float16 Asm[64 * KP1];
    __shared__ __attribute__((aligned(16))) _Float16 Bsm[128 * KP1];
    __shared__ float sdots[64][2][2];
    int tid = threadIdx.x;
    int n0 = (blockIdx.x - EB_BLOCKS) * 64;

    const float2* in2 = (const float2*)(in + (size_t)n0 * F_IN);
    for (int idx = tid; idx < 64 * (F_IN / 2); idx += 256) {
        int r = idx / (F_IN / 2), k2 = idx - r * (F_IN / 2);
        float2 v = (n0 + r < N_NODES) ? in2[idx] : make_float2(0.f, 0.f);
        Asm[r * KP1 + 2 * k2]     = (_Float16)v.x;
        Asm[r * KP1 + 2 * k2 + 1] = (_Float16)v.y;
    }
    for (int idx = tid; idx < 64 * (96 - F_IN); idx += 256) {
        int r = idx / (96 - F_IN), k = F_IN + idx - r * (96 - F_IN);
        Asm[r * KP1 + k] = (_Float16)0.f;
    }
    const float4* W4 = (const float4*)W;
    for (int idx = tid; idx < F_IN * 32; idx += 256) {
        float4 v = W4[idx];
        int k = idx >> 5, n = (idx & 31) * 4;
        Bsm[(n + 0) * KP1 + k] = (_Float16)v.x;
        Bsm[(n + 1) * KP1 + k] = (_Float16)v.y;
        Bsm[(n + 2) * KP1 + k] = (_Float16)v.z;
        Bsm[(n + 3) * KP1 + k] = (_Float16)v.w;
    }
    for (int idx = tid; idx < 128 * (96 - F_IN); idx += 256) {
        int n = idx / (96 - F_IN), k = F_IN + idx - n * (96 - F_IN);
        Bsm[n * KP1 + k] = (_Float16)0.f;
    }
    __syncthreads();

    int wave = tid >> 6, lane = tid & 63;
    int wm = (wave & 1) * 32, wn = (wave >> 1) * 64;
    int m16 = lane & 15, quad = lane >> 4;

    f4v acc[2][4];
#pragma unroll
    for (int t = 0; t < 2; ++t)
#pragma unroll
        for (int c = 0; c < 4; ++c) acc[t][c] = (f4v){0.f, 0.f, 0.f, 0.f};

#pragma unroll
    for (int kk = 0; kk < 96 / 32; ++kk) {
        int koff = kk * 32 + quad * 8;
        half8 a0 = *(const half8*)&Asm[(wm + m16) * KP1 + koff];
        half8 a1 = *(const half8*)&Asm[(wm + 16 + m16) * KP1 + koff];
#pragma unroll
        for (int c = 0; c < 4; ++c) {
            half8 b = *(const half8*)&Bsm[(wn + c * 16 + m16) * KP1 + koff];
            acc[0][c] = __builtin_amdgcn_mfma_f32_16x16x32_f16(a0, b, acc[0][c], 0, 0, 0);
            acc[1][c] = __builtin_amdgcn_mfma_f32_16x16x32_f16(a1, b, acc[1][c], 0, 0, 0);
        }
    }

    float asv[4], adv[4];
#pragma unroll
    for (int c = 0; c < 4; ++c) {
        asv[c] = a_s[wn + c * 16 + m16];
        adv[c] = a_d[wn + c * 16 + m16];
    }
#pragma unroll
    for (int t = 0; t < 2; ++t)
#pragma unroll
        for (int r = 0; r < 4; ++r) {
            float ps = 0.f, pd = 0.f;
#pragma unroll
            for (int c = 0; c < 4; ++c) {
                float v = acc[t][c][r];
                ps += v * asv[c];
                pd += v * adv[c];
            }
#pragma unroll
            for (int o = 1; o < 16; o <<= 1) {
                ps += __shfl_xor(ps, o);
                pd += __shfl_xor(pd, o);
            }
            if (m16 == 0) {
                int row = wm + t * 16 + quad * 4 + r;
                sdots[row][wn >> 6][0] = ps;
                sdots[row][wn >> 6][1] = pd;
            }
        }
#pragma unroll
    for (int t = 0; t < 2; ++t)
#pragma unroll
        for (int c = 0; c < 4; ++c)
#pragma unroll
            for (int r = 0; r < 4; ++r) {
                int row = n0 + wm + t * 16 + quad * 4 + r;
                if (row < N_NODES)
                    hout[(size_t)row * H_DIM + wn + c * 16 + m16] = (_Float16)acc[t][c][r];
            }
    __syncthreads();
    if (tid < 64) {
        int row = n0 + tid;
        if (row < N_NODES) {
            hs[row] = sdots[tid][0][0] + sdots[tid][1][0];
            hd[row] = sdots[tid][0][1] + sdots[tid][1][1];
        }
    }
}

// per-block inclusive scan -> excl (within-block exclusive) + block sums
__global__ void scan1(const int* __restrict__ cnt, int* __restrict__ excl,
                      int* __restrict__ bsum) {
    __shared__ int s[256];
    int tid = threadIdx.x;
    int i = blockIdx.x * 256 + tid;
    int v = (i < N_NODES) ? cnt[i] : 0;
    s[tid] = v;
    __syncthreads();
    for (int o = 1; o < 256; o <<= 1) {
        int t = (tid >= o) ? s[tid - o] : 0;
        __syncthreads();
        s[tid] += t;
        __syncthreads();
    }
    if (i < N_NODES) excl[i] = s[tid] - v;
    if (tid == 255) bsum[blockIdx.x] = s[255];
}

// merged scan2+scan3: every block scans the 196 block sums in LDS and
// writes its slice of row_ptr.
__global__ void scan23(const int* __restrict__ excl, const int* __restrict__ bsum,
                       int* __restrict__ row_ptr) {
    __shared__ int s[256];
    int tid = threadIdx.x;
    int v = (tid < SCAN_BLOCKS) ? bsum[tid] : 0;
    s[tid] = v;
    __syncthreads();
    for (int o = 1; o < 256; o <<= 1) {
        int t = (tid >= o) ? s[tid - o] : 0;
        __syncthreads();
        s[tid] += t;
        __syncthreads();
    }
    int boff = s[blockIdx.x] - bsum[blockIdx.x];
    int i = blockIdx.x * 256 + tid;
    if (i < N_NODES) row_ptr[i] = excl[i] + boff;
    if (i == 0) row_ptr[N_NODES] = N_EDGES;
}

// lite scatter: 1 edge/thread; all reads coalesced, one random 8 B store.
__global__ void scatter_lite(const int* __restrict__ src, const int* __restrict__ dst,
                             const int* __restrict__ row_ptr,
                             const unsigned short* __restrict__ rank,
                             const unsigned int* __restrict__ dotp,
                             int2* __restrict__ perm) {
    int e = blockIdx.x * blockDim.x + threadIdx.x;
    if (e >= N_EDGES) return;
    int pos = row_ptr[dst[e]] + rank[e];
    perm[pos] = make_int2(src[e], (int)dotp[e]);
}

// conv2 GEMM + fused node dots. fp16 input, K=128.
#define KP2 136
__global__ __launch_bounds__(256)
void gemm2(const _Float16* __restrict__ in, const float* __restrict__ W,
           const float* __restrict__ a_s, const float* __restrict__ a_d,
           _Float16* __restrict__ hout, float* __restrict__ hs, float* __restrict__ hd) {
    __shared__ __attribute__((aligned(16))) _Float16 Asm[64 * KP2];
    __shared__ __attribute__((aligned(16))) _Float16 Bsm[128 * KP2];
    __shared__ float sdots[64][2][2];
    int tid = threadIdx.x;
    int n0 = blockIdx.x * 64;

    const half8* in8 = (const half8*)(in + (size_t)n0 * H_DIM);
    for (int idx = tid; idx < 64 * 16; idx += 256) {
        int r = idx >> 4, k8 = idx & 15;
        half8 v = (n0 + r < N_NODES) ? in8[idx]
                                     : (half8){0, 0, 0, 0, 0, 0, 0, 0};
        *(half8*)&Asm[r * KP2 + k8 * 8] = v;
    }
    const float4* W4 = (const float4*)W;
    for (int idx = tid; idx < 128 * 32; idx += 256) {
        float4 v = W4[idx];
        int k = idx >> 5, n = (idx & 31) * 4;
        Bsm[(n + 0) * KP2 + k] = (_Float16)v.x;
        Bsm[(n + 1) * KP2 + k] = (_Float16)v.y;
        Bsm[(n + 2) * KP2 + k] = (_Float16)v.z;
        Bsm[(n + 3) * KP2 + k] = (_Float16)v.w;
    }
    __syncthreads();

    int wave = tid >> 6, lane = tid & 63;
    int wm = (wave & 1) * 32, wn = (wave >> 1) * 64;
    int m16 = lane & 15, quad = lane >> 4;

    f4v acc[2][4];
#pragma unroll
    for (int t = 0; t < 2; ++t)
#pragma unroll
        for (int c = 0; c < 4; ++c) acc[t][c] = (f4v){0.f, 0.f, 0.f, 0.f};

#pragma unroll
    for (int kk = 0; kk < 128 / 32; ++kk) {
        int koff = kk * 32 + quad * 8;
        half8 a0 = *(const half8*)&Asm[(wm + m16) * KP2 + koff];
        half8 a1 = *(const half8*)&Asm[(wm + 16 + m16) * KP2 + koff];
#pragma unroll
        for (int c = 0; c < 4; ++c) {
            half8 b = *(const half8*)&Bsm[(wn + c * 16 + m16) * KP2 + koff];
            acc[0][c] = __builtin_amdgcn_mfma_f32_16x16x32_f16(a0, b, acc[0][c], 0, 0, 0);
            acc[1][c] = __builtin_amdgcn_mfma_f32_16x16x32_f16(a1, b, acc[1][c], 0, 0, 0);
        }
    }

    float asv[4], adv[4];
#pragma unroll
    for (int c = 0; c < 4; ++c) {
        asv[c] = a_s[wn + c * 16 + m16];
        adv[c] = a_d[wn + c * 16 + m16];
    }
#pragma unroll
    for (int t = 0; t < 2; ++t)
#pragma unroll
        for (int r = 0; r < 4; ++r) {
            float ps = 0.f, pd = 0.f;
#pragma unroll
            for (int c = 0; c < 4; ++c) {
                float v = acc[t][c][r];
                ps += v * asv[c];
                pd += v * adv[c];
            }
#pragma unroll
            for (int o = 1; o < 16; o <<= 1) {
                ps += __shfl_xor(ps, o);
                pd += __shfl_xor(pd, o);
            }
            if (m16 == 0) {
                int row = wm + t * 16 + quad * 4 + r;
                sdots[row][wn >> 6][0] = ps;
                sdots[row][wn >> 6][1] = pd;
            }
        }
#pragma unroll
    for (int t = 0; t < 2; ++t)
#pragma unroll
        for (int c = 0; c < 4; ++c)
#pragma unroll
            for (int r = 0; r < 4; ++r) {
                int row = n0 + wm + t * 16 + quad * 4 + r;
                if (row < N_NODES)
                    hout[(size_t)row * H_DIM + wn + c * 16 + m16] = (_Float16)acc[t][c][r];
            }
    __syncthreads();
    if (tid < 64) {
        int row = n0 + tid;
        if (row < N_NODES) {
            hs[row] = sdots[tid][0][0] + sdots[tid][1][0];
            hd[row] = sdots[tid][0][1] + sdots[tid][1][1];
        }
    }
}

// One wave per dst node, single-pass softmax. POOL=false: write fp16 rows.
// POOL=true: fuse global max-pool (LDS block max + atomics; batch sorted,
// so ~99% of 4-node blocks are single-graph). N_NODES % 4 == 0 -> no tail.
template<int DOT, bool POOL>
__global__ void gat_node(const int* __restrict__ row_ptr, const int2* __restrict__ perm,
                         const float* __restrict__ hs, const float* __restrict__ hd,
                         const _Float16* __restrict__ h, const float* __restrict__ bias,
                         _Float16* __restrict__ out,
                         const int* __restrict__ batch, float* __restrict__ pooled) {
    __shared__ float smax[H_DIM];
    __shared__ int sg[4];
    int tid = threadIdx.x;
    if (POOL) {
        if (tid < H_DIM) smax[tid] = 0.f;
        __syncthreads();
    }
    int n = blockIdx.x * 4 + (tid >> 6);
    int lane = tid & 63;
    int q = lane >> 4, m = lane & 15;
    int r0 = row_ptr[n], r1 = row_ptr[n + 1];
    float hdn = hd[n];

    float acc[8];
#pragma unroll
    for (int k = 0; k < 8; ++k) acc[k] = 0.f;
    float denl = 0.f;

    for (int c = r0; c < r1; c += 64) {
        int i = c + lane;
        float w = 0.f;
        int s = 0;
        if (i < r1) {
            int2 p = perm[i];
            s = p.x;
            h2v dv = __builtin_bit_cast(h2v, p.y);
            float dotv = (DOT == 1) ? (float)dv.x : (float)dv.y;
            float t = hs[s] + hdn + dotv;
            t = (t > 0.f) ? t : NEG_SLOPE * t;
            w = __expf(t);
        }
        denl += w;
        int lim = min(64, r1 - c);
        int njj = (lim + 7) >> 3;
        for (int jj = 0; jj < njj; ++jj) {
            int j1 = (jj << 3) + q;
            int j2 = j1 + 4;
            float w1 = __shfl(w, j1);
            int   s1 = __shfl(s, j1);
            float w2 = __shfl(w, j2);
            int   s2 = __shfl(s, j2);
            half8 v1 = *(const half8*)&h[(size_t)s1 * H_DIM + m * 8];
            half8 v2 = *(const half8*)&h[(size_t)s2 * H_DIM + m * 8];
#pragma unroll
            for (int k = 0; k < 8; ++k) acc[k] += w1 * (float)v1[k];
#pragma unroll
            for (int k = 0; k < 8; ++k) acc[k] += w2 * (float)v2[k];
        }
    }
#pragma unroll
    for (int k = 0; k < 8; ++k) {
        acc[k] += __shfl_xor(acc[k], 16);
        acc[k] += __shfl_xor(acc[k], 32);
    }
    float den = denl;
#pragma unroll
    for (int o = 32; o > 0; o >>= 1) den += __shfl_xor(den, o);
    float inv = 1.f / fmaxf(den, 1e-16f);

    float rv[8];
    if (q == 0) {
        float4 b0 = ((const float4*)bias)[2 * m];
        float4 b1 = ((const float4*)bias)[2 * m + 1];
        rv[0] = fmaxf(acc[0] * inv + b0.x, 0.f);
        rv[1] = fmaxf(acc[1] * inv + b0.y, 0.f);
        rv[2] = fmaxf(acc[2] * inv + b0.z, 0.f);
        rv[3] = fmaxf(acc[3] * inv + b0.w, 0.f);
        rv[4] = fmaxf(acc[4] * inv + b1.x, 0.f);
        rv[5] = fmaxf(acc[5] * inv + b1.y, 0.f);
        rv[6] = fmaxf(acc[6] * inv + b1.z, 0.f);
        rv[7] = fmaxf(acc[7] * inv + b1.w, 0.f);
    }

    if (!POOL) {
        if (q == 0) {
            half8 ov;
#pragma unroll
            for (int k = 0; k < 8; ++k) ov[k] = (_Float16)rv[k];
            *(half8*)&out[(size_t)n * H_DIM + m * 8] = ov;
        }
    } else {
        int g = batch[n];
        if (lane == 0) sg[tid >> 6] = g;
        if (q == 0) {
#pragma unroll
            for (int k = 0; k < 8; ++k)
                atomicMax((int*)&smax[m * 8 + k], __float_as_int(rv[k]));  // rv >= 0
        }
        __syncthreads();
        if (sg[0] == sg[3]) {
            if (tid < H_DIM)
                atomicMaxFloat(&pooled[sg[0] * H_DIM + tid], smax[tid]);
        } else {
            if (q == 0) {
#pragma unroll
                for (int k = 0; k < 8; ++k)
                    atomicMaxFloat(&pooled[g * H_DIM + m * 8 + k], rv[k]);
            }
        }
    }
}

__global__ void final_logits(const float* __restrict__ pooled, const float* __restrict__ Wl,
                             const float* __restrict__ bl, float* __restrict__ outp) {
    int g = threadIdx.x;  // 64
    if (g >= G_GRAPHS) return;
    float lg[C_CLS];
#pragma unroll
    for (int c = 0; c < C_CLS; ++c) lg[c] = bl[c];
    for (int k = 0; k < H_DIM; ++k) {
        float v = pooled[g * H_DIM + k];
#pragma unroll
        for (int c = 0; c < C_CLS; ++c) lg[c] += v * Wl[k * C_CLS + c];
    }
    float mx = lg[0];
#pragma unroll
    for (int c = 1; c < C_CLS; ++c) mx = fmaxf(mx, lg[c]);
    float se = 0.f;
#pragma unroll
    for (int c = 0; c < C_CLS; ++c) se += expf(lg[c] - mx);
    float lse = logf(se);
#pragma unroll
    for (int c = 0; c < C_CLS; ++c) outp[g * C_CLS + c] = lg[c] - mx - lse;
}

extern "C" void kernel_launch(void* const* d_in, const int* in_sizes, int n_in,
                              void* d_out, int out_size, void* d_ws, size_t ws_size,
                              hipStream_t stream) {
    const float* x     = (const float*)d_in[0];
    const int*   eidx  = (const int*)d_in[1];
    const float* ea    = (const float*)d_in[2];
    const int*   batch = (const int*)d_in[3];
    const float* W1  = (const float*)d_in[4];
    const float* We1 = (const float*)d_in[5];
    const float* as1 = (const float*)d_in[6];
    const float* ad1 = (const float*)d_in[7];
    const float* ae1 = (const float*)d_in[8];
    const float* b1  = (const float*)d_in[9];
    const float* W2  = (const float*)d_in[10];
    const float* We2 = (const float*)d_in[11];
    const float* as2 = (const float*)d_in[12];
    const float* ad2 = (const float*)d_in[13];
    const float* ae2 = (const float*)d_in[14];
    const float* b2  = (const float*)d_in[15];
    const float* Wl  = (const float*)d_in[16];
    const float* bl  = (const float*)d_in[17];
    float* outp = (float*)d_out;

    const int* src = eidx;
    const int* dst = eidx + N_EDGES;

    char* wsb = (char*)d_ws;
    size_t off = 0;
    auto alloc = [&](size_t bytes) { char* p = wsb + off; off += (bytes + 255) & ~(size_t)255; return p; };
    _Float16* h    = (_Float16*)alloc((size_t)N_NODES * H_DIM * 2);
    _Float16* A2   = (_Float16*)alloc((size_t)N_NODES * H_DIM * 2);
    int2*  perm    = (int2*)alloc((size_t)N_EDGES * 8);
    unsigned short* rank = (unsigned short*)alloc((size_t)N_EDGES * 2);
    unsigned int* dotp = (unsigned int*)alloc((size_t)N_EDGES * 4);
    float* hs      = (float*)alloc(N_NODES * 4);
    float* hd      = (float*)alloc(N_NODES * 4);
    int*   row_ptr = (int*)alloc((N_NODES + 1) * 4);
    int*   cnt     = (int*)alloc(N_NODES * 4);
    int*   excl    = (int*)alloc(N_NODES * 4);
    int*   bsum    = (int*)alloc(SCAN_BLOCKS * 4);
    float* pooled  = (float*)alloc(G_GRAPHS * H_DIM * 4);
    float* ve1     = (float*)alloc(16 * 4);
    float* ve2     = (float*)alloc(16 * 4);

    const int NB4 = (N_NODES + 3) / 4;

    // prep, then CSR-hist fused with conv1 GEMM (independent work overlapped)
    prep<<<SCAN_BLOCKS + 1, 256, 0, stream>>>(cnt, pooled, We1, ae1, We2, ae2, ve1, ve2);
    hist_gemm1<<<EB_BLOCKS + GB_BLOCKS, 256, 0, stream>>>(dst, cnt, rank, ea, ve1, ve2,
                                                          dotp, x, W1, as1, ad1, h, hs, hd);
    scan1<<<SCAN_BLOCKS, 256, 0, stream>>>(cnt, excl, bsum);
    scan23<<<SCAN_BLOCKS, 256, 0, stream>>>(excl, bsum, row_ptr);
    scatter_lite<<<EB_BLOCKS, 256, 0, stream>>>(src, dst, row_ptr, rank, dotp, perm);

    // ---- conv1 aggregate ----
    gat_node<1, false><<<NB4, 256, 0, stream>>>(row_ptr, perm, hs, hd, h, b1, A2,
                                                batch, pooled);

    // ---- conv2 ----
    gemm2<<<GB_BLOCKS, 256, 0, stream>>>(A2, W2, as2, ad2, h, hs, hd);
    gat_node<2, true><<<NB4, 256, 0, stream>>>(row_ptr, perm, hs, hd, h, b2, nullptr,
                                               batch, pooled);

    // ---- classifier ----
    final_logits<<<1, 64, 0, stream>>>(pooled, Wl, bl, outp);
}

// Round 12
// 314.537 us; speedup vs baseline: 1.6031x; 1.0401x over previous
//
#include <hip/hip_runtime.h>
#include <math.h>

#define N_NODES 50000
#define N_EDGES 800000
#define F_IN    86
#define H_DIM   128
#define ED_DIM  16
#define C_CLS   18
#define G_GRAPHS 64
#define NEG_SLOPE 0.2f
#define SCAN_BLOCKS ((N_NODES + 255) / 256)   // 196
#define EB_BLOCKS ((N_EDGES + 255) / 256)     // 3125
#define GB_BLOCKS ((N_NODES + 63) / 64)       // 782

typedef _Float16 h2v   __attribute__((ext_vector_type(2)));
typedef _Float16 half8 __attribute__((ext_vector_type(8)));
typedef float    f4v   __attribute__((ext_vector_type(4)));

__device__ __forceinline__ void atomicMaxFloat(float* addr, float val) {
    if (val >= 0.0f) atomicMax((int*)addr, __float_as_int(val));
    else             atomicMin((unsigned int*)addr, __float_as_uint(val));
}

// zero cnt (blocks 0..SCAN_BLOCKS-1); ve1/ve2 + zero pooled (block SCAN_BLOCKS)
__global__ void prep(int* __restrict__ cnt, float* __restrict__ pooled,
                     const float* __restrict__ We1, const float* __restrict__ ae1,
                     const float* __restrict__ We2, const float* __restrict__ ae2,
                     float* __restrict__ ve1, float* __restrict__ ve2) {
    int b = blockIdx.x, t = threadIdx.x;
    if (b < SCAN_BLOCKS) {
        int i = b * 256 + t;
        if (i < N_NODES) cnt[i] = 0;
    } else {
        if (t < ED_DIM) {
            float s = 0.f;
            for (int h = 0; h < H_DIM; ++h) s += We1[t * H_DIM + h] * ae1[h];
            ve1[t] = s;
        } else if (t < 2 * ED_DIM) {
            int j = t - ED_DIM;
            float s = 0.f;
            for (int h = 0; h < H_DIM; ++h) s += We2[j * H_DIM + h] * ae2[h];
            ve2[j] = s;
        }
        for (int i = t; i < G_GRAPHS * H_DIM; i += 256) pooled[i] = 0.f;
    }
}

// lean histogram + per-edge rank + edge-attr dots (16 VGPR, no LDS -> high
// occupancy for the atomic-latency-bound part; ea read hides behind atomics)
__global__ void hist_rank_dots(const int* __restrict__ dst, int* __restrict__ cnt,
                               unsigned short* __restrict__ rank,
                               const float* __restrict__ ea,
                               const float* __restrict__ ve1, const float* __restrict__ ve2,
                               unsigned int* __restrict__ dotp) {
    int e = blockIdx.x * blockDim.x + threadIdx.x;
    if (e >= N_EDGES) return;
    int r = atomicAdd(&cnt[dst[e]], 1);
    rank[e] = (unsigned short)r;
    const float4* p = (const float4*)(ea + (size_t)e * ED_DIM);
    float4 v0 = p[0], v1 = p[1], v2 = p[2], v3 = p[3];
    float s1 = v0.x*ve1[0] + v0.y*ve1[1] + v0.z*ve1[2] + v0.w*ve1[3]
             + v1.x*ve1[4] + v1.y*ve1[5] + v1.z*ve1[6] + v1.w*ve1[7]
             + v2.x*ve1[8] + v2.y*ve1[9] + v2.z*ve1[10] + v2.w*ve1[11]
             + v3.x*ve1[12] + v3.y*ve1[13] + v3.z*ve1[14] + v3.w*ve1[15];
    float s2 = v0.x*ve2[0] + v0.y*ve2[1] + v0.z*ve2[2] + v0.w*ve2[3]
             + v1.x*ve2[4] + v1.y*ve2[5] + v1.z*ve2[6] + v1.w*ve2[7]
             + v2.x*ve2[8] + v2.y*ve2[9] + v2.z*ve2[10] + v2.w*ve2[11]
             + v3.x*ve2[12] + v3.y*ve2[13] + v3.z*ve2[14] + v3.w*ve2[15];
    h2v dv;
    dv.x = (_Float16)s1;
    dv.y = (_Float16)s2;
    dotp[e] = __builtin_bit_cast(unsigned int, dv);
}

// per-block inclusive scan -> excl (within-block exclusive) + block sums
__global__ void scan1(const int* __restrict__ cnt, int* __restrict__ excl,
                      int* __restrict__ bsum) {
    __shared__ int s[256];
    int tid = threadIdx.x;
    int i = blockIdx.x * 256 + tid;
    int v = (i < N_NODES) ? cnt[i] : 0;
    s[tid] = v;
    __syncthreads();
    for (int o = 1; o < 256; o <<= 1) {
        int t = (tid >= o) ? s[tid - o] : 0;
        __syncthreads();
        s[tid] += t;
        __syncthreads();
    }
    if (i < N_NODES) excl[i] = s[tid] - v;
    if (tid == 255) bsum[blockIdx.x] = s[255];
}

// merged scan2+scan3: every block scans the 196 block sums in LDS and
// writes its slice of row_ptr.
__global__ void scan23(const int* __restrict__ excl, const int* __restrict__ bsum,
                       int* __restrict__ row_ptr) {
    __shared__ int s[256];
    int tid = threadIdx.x;
    int v = (tid < SCAN_BLOCKS) ? bsum[tid] : 0;
    s[tid] = v;
    __syncthreads();
    for (int o = 1; o < 256; o <<= 1) {
        int t = (tid >= o) ? s[tid - o] : 0;
        __syncthreads();
        s[tid] += t;
        __syncthreads();
    }
    int boff = s[blockIdx.x] - bsum[blockIdx.x];
    int i = blockIdx.x * 256 + tid;
    if (i < N_NODES) row_ptr[i] = excl[i] + boff;
    if (i == 0) row_ptr[N_NODES] = N_EDGES;
}

// lite scatter: 1 edge/thread; all reads coalesced, one random 8 B store.
__global__ void scatter_lite(const int* __restrict__ src, const int* __restrict__ dst,
                             const int* __restrict__ row_ptr,
                             const unsigned short* __restrict__ rank,
                             const unsigned int* __restrict__ dotp,
                             int2* __restrict__ perm) {
    int e = blockIdx.x * blockDim.x + threadIdx.x;
    if (e >= N_EDGES) return;
    int pos = row_ptr[dst[e]] + rank[e];
    perm[pos] = make_int2(src[e], (int)dotp[e]);
}

// conv1 GEMM + fused node dots. h = fp16(x @ W1), K=86 padded to 96.
#define KP1 104
__global__ __launch_bounds__(256)
void gemm1(const float* __restrict__ in, const float* __restrict__ W,
           const float* __restrict__ a_s, const float* __restrict__ a_d,
           _Float16* __restrict__ hout, float* __restrict__ hs, float* __restrict__ hd) {
    __shared__ __attribute__((aligned(16))) _Float16 Asm[64 * KP1];
    __shared__ __attribute__((aligned(16))) _Float16 Bsm[128 * KP1];
    __shared__ float sdots[64][2][2];
    int tid = threadIdx.x;
    int n0 = blockIdx.x * 64;

    const float2* in2 = (const float2*)(in + (size_t)n0 * F_IN);
    for (int idx = tid; idx < 64 * (F_IN / 2); idx += 256) {
        int r = idx / (F_IN / 2), k2 = idx - r * (F_IN / 2);
        float2 v = (n0 + r < N_NODES) ? in2[idx] : make_float2(0.f, 0.f);
        Asm[r * KP1 + 2 * k2]     = (_Float16)v.x;
        Asm[r * KP1 + 2 * k2 + 1] = (_Float16)v.y;
    }
    for (int idx = tid; idx < 64 * (96 - F_IN); idx += 256) {
        int r = idx / (96 - F_IN), k = F_IN + idx - r * (96 - F_IN);
        Asm[r * KP1 + k] = (_Float16)0.f;
    }
    const float4* W4 = (const float4*)W;
    for (int idx = tid; idx < F_IN * 32; idx += 256) {
        float4 v = W4[idx];
        int k = idx >> 5, n = (idx & 31) * 4;
        Bsm[(n + 0) * KP1 + k] = (_Float16)v.x;
        Bsm[(n + 1) * KP1 + k] = (_Float16)v.y;
        Bsm[(n + 2) * KP1 + k] = (_Float16)v.z;
        Bsm[(n + 3) * KP1 + k] = (_Float16)v.w;
    }
    for (int idx = tid; idx < 128 * (96 - F_IN); idx += 256) {
        int n = idx / (96 - F_IN), k = F_IN + idx - n * (96 - F_IN);
        Bsm[n * KP1 + k] = (_Float16)0.f;
    }
    __syncthreads();

    int wave = tid >> 6, lane = tid & 63;
    int wm = (wave & 1) * 32, wn = (wave >> 1) * 64;
    int m16 = lane & 15, quad = lane >> 4;

    f4v acc[2][4];
#pragma unroll
    for (int t = 0; t < 2; ++t)
#pragma unroll
        for (int c = 0; c < 4; ++c) acc[t][c] = (f4v){0.f, 0.f, 0.f, 0.f};

#pragma unroll
    for (int kk = 0; kk < 96 / 32; ++kk) {
        int koff = kk * 32 + quad * 8;
        half8 a0 = *(const half8*)&Asm[(wm + m16) * KP1 + koff];
        half8 a1 = *(const half8*)&Asm[(wm + 16 + m16) * KP1 + koff];
#pragma unroll
        for (int c = 0; c < 4; ++c) {
            half8 b = *(const half8*)&Bsm[(wn + c * 16 + m16) * KP1 + koff];
            acc[0][c] = __builtin_amdgcn_mfma_f32_16x16x32_f16(a0, b, acc[0][c], 0, 0, 0);
            acc[1][c] = __builtin_amdgcn_mfma_f32_16x16x32_f16(a1, b, acc[1][c], 0, 0, 0);
        }
    }

    float asv[4], adv[4];
#pragma unroll
    for (int c = 0; c < 4; ++c) {
        asv[c] = a_s[wn + c * 16 + m16];
        adv[c] = a_d[wn + c * 16 + m16];
    }
#pragma unroll
    for (int t = 0; t < 2; ++t)
#pragma unroll
        for (int r = 0; r < 4; ++r) {
            float ps = 0.f, pd = 0.f;
#pragma unroll
            for (int c = 0; c < 4; ++c) {
                float v = acc[t][c][r];
                ps += v * asv[c];
                pd += v * adv[c];
            }
#pragma unroll
            for (int o = 1; o < 16; o <<= 1) {
                ps += __shfl_xor(ps, o);
                pd += __shfl_xor(pd, o);
            }
            if (m16 == 0) {
                int row = wm + t * 16 + quad * 4 + r;
                sdots[row][wn >> 6][0] = ps;
                sdots[row][wn >> 6][1] = pd;
            }
        }
#pragma unroll
    for (int t = 0; t < 2; ++t)
#pragma unroll
        for (int c = 0; c < 4; ++c)
#pragma unroll
            for (int r = 0; r < 4; ++r) {
                int row = n0 + wm + t * 16 + quad * 4 + r;
                if (row < N_NODES)
                    hout[(size_t)row * H_DIM + wn + c * 16 + m16] = (_Float16)acc[t][c][r];
            }
    __syncthreads();
    if (tid < 64) {
        int row = n0 + tid;
        if (row < N_NODES) {
            hs[row] = sdots[tid][0][0] + sdots[tid][1][0];
            hd[row] = sdots[tid][0][1] + sdots[tid][1][1];
        }
    }
}

// conv2 GEMM + fused node dots. fp16 input, K=128.
#define KP2 136
__global__ __launch_bounds__(256)
void gemm2(const _Float16* __restrict__ in, const float* __restrict__ W,
           const float* __restrict__ a_s, const float* __restrict__ a_d,
           _Float16* __restrict__ hout, float* __restrict__ hs, float* __restrict__ hd) {
    __shared__ __attribute__((aligned(16))) _Float16 Asm[64 * KP2];
    __shared__ __attribute__((aligned(16))) _Float16 Bsm[128 * KP2];
    __shared__ float sdots[64][2][2];
    int tid = threadIdx.x;
    int n0 = blockIdx.x * 64;

    const half8* in8 = (const half8*)(in + (size_t)n0 * H_DIM);
    for (int idx = tid; idx < 64 * 16; idx += 256) {
        int r = idx >> 4, k8 = idx & 15;
        half8 v = (n0 + r < N_NODES) ? in8[idx]
                                     : (half8){0, 0, 0, 0, 0, 0, 0, 0};
        *(half8*)&Asm[r * KP2 + k8 * 8] = v;
    }
    const float4* W4 = (const float4*)W;
    for (int idx = tid; idx < 128 * 32; idx += 256) {
        float4 v = W4[idx];
        int k = idx >> 5, n = (idx & 31) * 4;
        Bsm[(n + 0) * KP2 + k] = (_Float16)v.x;
        Bsm[(n + 1) * KP2 + k] = (_Float16)v.y;
        Bsm[(n + 2) * KP2 + k] = (_Float16)v.z;
        Bsm[(n + 3) * KP2 + k] = (_Float16)v.w;
    }
    __syncthreads();

    int wave = tid >> 6, lane = tid & 63;
    int wm = (wave & 1) * 32, wn = (wave >> 1) * 64;
    int m16 = lane & 15, quad = lane >> 4;

    f4v acc[2][4];
#pragma unroll
    for (int t = 0; t < 2; ++t)
#pragma unroll
        for (int c = 0; c < 4; ++c) acc[t][c] = (f4v){0.f, 0.f, 0.f, 0.f};

#pragma unroll
    for (int kk = 0; kk < 128 / 32; ++kk) {
        int koff = kk * 32 + quad * 8;
        half8 a0 = *(const half8*)&Asm[(wm + m16) * KP2 + koff];
        half8 a1 = *(const half8*)&Asm[(wm + 16 + m16) * KP2 + koff];
#pragma unroll
        for (int c = 0; c < 4; ++c) {
            half8 b = *(const half8*)&Bsm[(wn + c * 16 + m16) * KP2 + koff];
            acc[0][c] = __builtin_amdgcn_mfma_f32_16x16x32_f16(a0, b, acc[0][c], 0, 0, 0);
            acc[1][c] = __builtin_amdgcn_mfma_f32_16x16x32_f16(a1, b, acc[1][c], 0, 0, 0);
        }
    }

    float asv[4], adv[4];
#pragma unroll
    for (int c = 0; c < 4; ++c) {
        asv[c] = a_s[wn + c * 16 + m16];
        adv[c] = a_d[wn + c * 16 + m16];
    }
#pragma unroll
    for (int t = 0; t < 2; ++t)
#pragma unroll
        for (int r = 0; r < 4; ++r) {
            float ps = 0.f, pd = 0.f;
#pragma unroll
            for (int c = 0; c < 4; ++c) {
                float v = acc[t][c][r];
                ps += v * asv[c];
                pd += v * adv[c];
            }
#pragma unroll
            for (int o = 1; o < 16; o <<= 1) {
                ps += __shfl_xor(ps, o);
                pd += __shfl_xor(pd, o);
            }
            if (m16 == 0) {
                int row = wm + t * 16 + quad * 4 + r;
                sdots[row][wn >> 6][0] = ps;
                sdots[row][wn >> 6][1] = pd;
            }
        }
#pragma unroll
    for (int t = 0; t < 2; ++t)
#pragma unroll
        for (int c = 0; c < 4; ++c)
#pragma unroll
            for (int r = 0; r < 4; ++r) {
                int row = n0 + wm + t * 16 + quad * 4 + r;
                if (row < N_NODES)
                    hout[(size_t)row * H_DIM + wn + c * 16 + m16] = (_Float16)acc[t][c][r];
            }
    __syncthreads();
    if (tid < 64) {
        int row = n0 + tid;
        if (row < N_NODES) {
            hs[row] = sdots[tid][0][0] + sdots[tid][1][0];
            hd[row] = sdots[tid][0][1] + sdots[tid][1][1];
        }
    }
}

// One wave per dst node, single-pass softmax. POOL=false: write fp16 rows.
// POOL=true: fuse global max-pool (LDS block max + atomics; batch sorted,
// so ~99% of 4-node blocks are single-graph). N_NODES % 4 == 0 -> no tail.
template<int DOT, bool POOL>
__global__ void gat_node(const int* __restrict__ row_ptr, const int2* __restrict__ perm,
                         const float* __restrict__ hs, const float* __restrict__ hd,
                         const _Float16* __restrict__ h, const float* __restrict__ bias,
                         _Float16* __restrict__ out,
                         const int* __restrict__ batch, float* __restrict__ pooled) {
    __shared__ float smax[H_DIM];
    __shared__ int sg[4];
    int tid = threadIdx.x;
    if (POOL) {
        if (tid < H_DIM) smax[tid] = 0.f;
        __syncthreads();
    }
    int n = blockIdx.x * 4 + (tid >> 6);
    int lane = tid & 63;
    int q = lane >> 4, m = lane & 15;
    int r0 = row_ptr[n], r1 = row_ptr[n + 1];
    float hdn = hd[n];

    float acc[8];
#pragma unroll
    for (int k = 0; k < 8; ++k) acc[k] = 0.f;
    float denl = 0.f;

    for (int c = r0; c < r1; c += 64) {
        int i = c + lane;
        float w = 0.f;
        int s = 0;
        if (i < r1) {
            int2 p = perm[i];
            s = p.x;
            h2v dv = __builtin_bit_cast(h2v, p.y);
            float dotv = (DOT == 1) ? (float)dv.x : (float)dv.y;
            float t = hs[s] + hdn + dotv;
            t = (t > 0.f) ? t : NEG_SLOPE * t;
            w = __expf(t);
        }
        denl += w;
        int lim = min(64, r1 - c);
        int njj = (lim + 7) >> 3;
        for (int jj = 0; jj < njj; ++jj) {
            int j1 = (jj << 3) + q;
            int j2 = j1 + 4;
            float w1 = __shfl(w, j1);
            int   s1 = __shfl(s, j1);
            float w2 = __shfl(w, j2);
            int   s2 = __shfl(s, j2);
            half8 v1 = *(const half8*)&h[(size_t)s1 * H_DIM + m * 8];
            half8 v2 = *(const half8*)&h[(size_t)s2 * H_DIM + m * 8];
#pragma unroll
            for (int k = 0; k < 8; ++k) acc[k] += w1 * (float)v1[k];
#pragma unroll
            for (int k = 0; k < 8; ++k) acc[k] += w2 * (float)v2[k];
        }
    }
#pragma unroll
    for (int k = 0; k < 8; ++k) {
        acc[k] += __shfl_xor(acc[k], 16);
        acc[k] += __shfl_xor(acc[k], 32);
    }
    float den = denl;
#pragma unroll
    for (int o = 32; o > 0; o >>= 1) den += __shfl_xor(den, o);
    float inv = 1.f / fmaxf(den, 1e-16f);

    float rv[8];
    if (q == 0) {
        float4 b0 = ((const float4*)bias)[2 * m];
        float4 b1 = ((const float4*)bias)[2 * m + 1];
        rv[0] = fmaxf(acc[0] * inv + b0.x, 0.f);
        rv[1] = fmaxf(acc[1] * inv + b0.y, 0.f);
        rv[2] = fmaxf(acc[2] * inv + b0.z, 0.f);
        rv[3] = fmaxf(acc[3] * inv + b0.w, 0.f);
        rv[4] = fmaxf(acc[4] * inv + b1.x, 0.f);
        rv[5] = fmaxf(acc[5] * inv + b1.y, 0.f);
        rv[6] = fmaxf(acc[6] * inv + b1.z, 0.f);
        rv[7] = fmaxf(acc[7] * inv + b1.w, 0.f);
    }

    if (!POOL) {
        if (q == 0) {
            half8 ov;
#pragma unroll
            for (int k = 0; k < 8; ++k) ov[k] = (_Float16)rv[k];
            *(half8*)&out[(size_t)n * H_DIM + m * 8] = ov;
        }
    } else {
        int g = batch[n];
        if (lane == 0) sg[tid >> 6] = g;
        if (q == 0) {
#pragma unroll
            for (int k = 0; k < 8; ++k)
                atomicMax((int*)&smax[m * 8 + k], __float_as_int(rv[k]));  // rv >= 0
        }
        __syncthreads();
        if (sg[0] == sg[3]) {
            if (tid < H_DIM)
                atomicMaxFloat(&pooled[sg[0] * H_DIM + tid], smax[tid]);
        } else {
            if (q == 0) {
#pragma unroll
                for (int k = 0; k < 8; ++k)
                    atomicMaxFloat(&pooled[g * H_DIM + m * 8 + k], rv[k]);
            }
        }
    }
}

__global__ void final_logits(const float* __restrict__ pooled, const float* __restrict__ Wl,
                             const float* __restrict__ bl, float* __restrict__ outp) {
    int g = threadIdx.x;  // 64
    if (g >= G_GRAPHS) return;
    float lg[C_CLS];
#pragma unroll
    for (int c = 0; c < C_CLS; ++c) lg[c] = bl[c];
    for (int k = 0; k < H_DIM; ++k) {
        float v = pooled[g * H_DIM + k];
#pragma unroll
        for (int c = 0; c < C_CLS; ++c) lg[c] += v * Wl[k * C_CLS + c];
    }
    float mx = lg[0];
#pragma unroll
    for (int c = 1; c < C_CLS; ++c) mx = fmaxf(mx, lg[c]);
    float se = 0.f;
#pragma unroll
    for (int c = 0; c < C_CLS; ++c) se += expf(lg[c] - mx);
    float lse = logf(se);
#pragma unroll
    for (int c = 0; c < C_CLS; ++c) outp[g * C_CLS + c] = lg[c] - mx - lse;
}

extern "C" void kernel_launch(void* const* d_in, const int* in_sizes, int n_in,
                              void* d_out, int out_size, void* d_ws, size_t ws_size,
                              hipStream_t stream) {
    const float* x     = (const float*)d_in[0];
    const int*   eidx  = (const int*)d_in[1];
    const float* ea    = (const float*)d_in[2];
    const int*   batch = (const int*)d_in[3];
    const float* W1  = (const float*)d_in[4];
    const float* We1 = (const float*)d_in[5];
    const float* as1 = (const float*)d_in[6];
    const float* ad1 = (const float*)d_in[7];
    const float* ae1 = (const float*)d_in[8];
    const float* b1  = (const float*)d_in[9];
    const float* W2  = (const float*)d_in[10];
    const float* We2 = (const float*)d_in[11];
    const float* as2 = (const float*)d_in[12];
    const float* ad2 = (const float*)d_in[13];
    const float* ae2 = (const float*)d_in[14];
    const float* b2  = (const float*)d_in[15];
    const float* Wl  = (const float*)d_in[16];
    const float* bl  = (const float*)d_in[17];
    float* outp = (float*)d_out;

    const int* src = eidx;
    const int* dst = eidx + N_EDGES;

    char* wsb = (char*)d_ws;
    size_t off = 0;
    auto alloc = [&](size_t bytes) { char* p = wsb + off; off += (bytes + 255) & ~(size_t)255; return p; };
    _Float16* h    = (_Float16*)alloc((size_t)N_NODES * H_DIM * 2);
    _Float16* A2   = (_Float16*)alloc((size_t)N_NODES * H_DIM * 2);
    int2*  perm    = (int2*)alloc((size_t)N_EDGES * 8);
    unsigned short* rank = (unsigned short*)alloc((size_t)N_EDGES * 2);
    unsigned int* dotp = (unsigned int*)alloc((size_t)N_EDGES * 4);
    float* hs      = (float*)alloc(N_NODES * 4);
    float* hd      = (float*)alloc(N_NODES * 4);
    int*   row_ptr = (int*)alloc((N_NODES + 1) * 4);
    int*   cnt     = (int*)alloc(N_NODES * 4);
    int*   excl    = (int*)alloc(N_NODES * 4);
    int*   bsum    = (int*)alloc(SCAN_BLOCKS * 4);
    float* pooled  = (float*)alloc(G_GRAPHS * H_DIM * 4);
    float* ve1     = (float*)alloc(16 * 4);
    float* ve2     = (float*)alloc(16 * 4);

    const int NB4 = (N_NODES + 3) / 4;

    // prep + CSR build (lean hist, rank trick, lite scatter)
    prep<<<SCAN_BLOCKS + 1, 256, 0, stream>>>(cnt, pooled, We1, ae1, We2, ae2, ve1, ve2);
    hist_rank_dots<<<EB_BLOCKS, 256, 0, stream>>>(dst, cnt, rank, ea, ve1, ve2, dotp);
    scan1<<<SCAN_BLOCKS, 256, 0, stream>>>(cnt, excl, bsum);
    scan23<<<SCAN_BLOCKS, 256, 0, stream>>>(excl, bsum, row_ptr);
    scatter_lite<<<EB_BLOCKS, 256, 0, stream>>>(src, dst, row_ptr, rank, dotp, perm);

    // ---- conv1 ----
    gemm1<<<GB_BLOCKS, 256, 0, stream>>>(x, W1, as1, ad1, h, hs, hd);
    gat_node<1, false><<<NB4, 256, 0, stream>>>(row_ptr, perm, hs, hd, h, b1, A2,
                                                batch, pooled);

    // ---- conv2 ----
    gemm2<<<GB_BLOCKS, 256, 0, stream>>>(A2, W2, as2, ad2, h, hs, hd);
    gat_node<2, true><<<NB4, 256, 0, stream>>>(row_ptr, perm, hs, hd, h, b2, nullptr,
                                               batch, pooled);

    // ---- classifier ----
    final_logits<<<1, 64, 0, stream>>>(pooled, Wl, bl, outp);
}